// Round 1
// baseline (5594.936 us; speedup 1.0000x reference)
//
#include <hip/hip_runtime.h>
#include <hip/hip_bf16.h>
#include <cstdint>

#define BB 128
#define TT 20
#define VV 10000
#define DD 1024
#define NHH 8
#define DHH 128
#define NN 196

typedef float f32x4 __attribute__((ext_vector_type(4)));
typedef __bf16 bf16x8 __attribute__((ext_vector_type(8)));
typedef unsigned int u32x4 __attribute__((ext_vector_type(4)));

__device__ __forceinline__ unsigned short f2bf(float x) {
  unsigned u = __float_as_uint(x);
  u += 0x7FFFu + ((u >> 16) & 1u);
  return (unsigned short)(u >> 16);
}
__device__ __forceinline__ float bf2f(unsigned short h) {
  return __uint_as_float(((unsigned)h) << 16);
}
__device__ __forceinline__ float sigm(float x) { return 1.f / (1.f + __expf(-x)); }
__device__ __forceinline__ unsigned pk2(float lo, float hi) {
  return (unsigned)f2bf(lo) | ((unsigned)f2bf(hi) << 16);
}

// ---- GEMM: C[M,N] = A[M,K] @ W[N,K]^T + bias ----
// MODE 0: fp32 out (ldc=N).  MODE 1: bf16 out (ldc=N).  MODE 2: preds -> d_out[B,T,V] w/ mask.
// AF32: A operand is fp32 (converted to bf16 during staging).
template<int MODE, bool AF32>
__launch_bounds__(256)
__global__ void gemm_bt(const void* __restrict__ Ain, const unsigned short* __restrict__ W,
                        const float* __restrict__ bias,
                        float* __restrict__ Cf, unsigned short* __restrict__ Cb,
                        int N, int K, const int* __restrict__ lengths, int tstep)
{
  __shared__ unsigned short As[128][40];   // +8 pad: breaks 64B-stride bank aliasing
  __shared__ unsigned short Bs[128][40];
  const int tid = threadIdx.x;
  const int rowbase = blockIdx.y * 128;
  const int colbase = blockIdx.x * 128;
  const int lane = tid & 63, wv = tid >> 6;
  const int wm = (wv >> 1) * 64, wn = (wv & 1) * 64;
  const int lr = lane & 15, lk = (lane >> 4) * 8;

  f32x4 acc[4][4];
  const f32x4 zero = {0.f, 0.f, 0.f, 0.f};
  #pragma unroll
  for (int i = 0; i < 4; ++i)
    #pragma unroll
    for (int j = 0; j < 4; ++j) acc[i][j] = zero;

  const int nkt = K >> 5;
  for (int kt = 0; kt < nkt; ++kt) {
    const int k0 = kt << 5;
    #pragma unroll
    for (int s = 0; s < 2; ++s) {
      const int c = tid * 2 + s;          // 512 16B-chunks: 128 rows x 4 chunks
      const int r = c >> 2, off2 = (c & 3) << 3;
      u32x4 va;
      if constexpr (AF32) {
        const float* ap = (const float*)Ain + (size_t)(rowbase + r) * K + k0 + off2;
        f32x4 f0 = *reinterpret_cast<const f32x4*>(ap);
        f32x4 f1 = *reinterpret_cast<const f32x4*>(ap + 4);
        u32x4 t = { pk2(f0[0], f0[1]), pk2(f0[2], f0[3]), pk2(f1[0], f1[1]), pk2(f1[2], f1[3]) };
        va = t;
      } else {
        va = *reinterpret_cast<const u32x4*>((const unsigned short*)Ain + (size_t)(rowbase + r) * K + k0 + off2);
      }
      int wr = colbase + r;
      if (MODE == 2) wr = wr < N ? wr : N - 1;   // clamp (N=10000 tail)
      u32x4 vb = *reinterpret_cast<const u32x4*>(W + (size_t)wr * K + k0 + off2);
      *reinterpret_cast<u32x4*>(&As[r][off2]) = va;
      *reinterpret_cast<u32x4*>(&Bs[r][off2]) = vb;
    }
    __syncthreads();
    bf16x8 af[4], bfr[4];
    #pragma unroll
    for (int i = 0; i < 4; ++i) af[i] = *reinterpret_cast<const bf16x8*>(&As[wm + i * 16 + lr][lk]);
    #pragma unroll
    for (int j = 0; j < 4; ++j) bfr[j] = *reinterpret_cast<const bf16x8*>(&Bs[wn + j * 16 + lr][lk]);
    #pragma unroll
    for (int i = 0; i < 4; ++i)
      #pragma unroll
      for (int j = 0; j < 4; ++j)
        acc[i][j] = __builtin_amdgcn_mfma_f32_16x16x32_bf16(af[i], bfr[j], acc[i][j], 0, 0, 0);
    __syncthreads();
  }

  #pragma unroll
  for (int i = 0; i < 4; ++i) {
    const int growb = rowbase + wm + i * 16 + (lane >> 4) * 4;
    #pragma unroll
    for (int j = 0; j < 4; ++j) {
      const int gcol = colbase + wn + j * 16 + (lane & 15);
      if (MODE == 2 && gcol >= N) continue;
      const float bv = bias[gcol];
      #pragma unroll
      for (int r = 0; r < 4; ++r) {
        const float val = acc[i][j][r] + bv;
        const int gr = growb + r;
        if (MODE == 0) {
          Cf[(size_t)gr * N + gcol] = val;
        } else if (MODE == 1) {
          Cb[(size_t)gr * N + gcol] = f2bf(val);
        } else {
          Cf[((size_t)gr * TT + tstep) * VV + gcol] = (tstep < lengths[gr]) ? val : 0.f;
        }
      }
    }
  }
}

// ---- pointwise / prep kernels ----
__launch_bounds__(256)
__global__ void conv_kernel(const float* __restrict__ src, unsigned short* __restrict__ dst, int n) {
  int i = blockIdx.x * 256 + threadIdx.x;
  if (i < n) dst[i] = f2bf(src[i]);
}

__launch_bounds__(256)
__global__ void wcat_kernel(const float* __restrict__ W_ih, const float* __restrict__ W_hh,
                            unsigned short* __restrict__ Wcat) {
  int idx = blockIdx.x * 256 + threadIdx.x;   // 4096*3072
  int r = idx / 3072, c = idx - r * 3072;
  float x = (c < 2048) ? W_ih[(size_t)r * 2048 + c] : W_hh[(size_t)r * 1024 + (c - 2048)];
  Wcat[idx] = f2bf(x);
}

__launch_bounds__(256)
__global__ void bcomb_kernel(const float* __restrict__ b_ih, const float* __restrict__ b_hh,
                             float* __restrict__ bc) {
  int i = blockIdx.x * 256 + threadIdx.x;
  if (i < 4096) bc[i] = b_ih[i] + b_hh[i];
}

__launch_bounds__(256)
__global__ void mean_kernel(const float* __restrict__ enc, float* __restrict__ meanf) {
  int idx = blockIdx.x * 256 + threadIdx.x;   // 128*1024
  int b = idx >> 10, d = idx & 1023;
  const float* p = enc + (size_t)b * NN * DD + d;
  float s = 0.f;
  for (int n = 0; n < NN; ++n) s += p[(size_t)n * DD];
  meanf[idx] = s * (1.0f / (float)NN);
}

__launch_bounds__(256)
__global__ void init_kernel(const float* __restrict__ meanf, float* __restrict__ m,
                            unsigned short* __restrict__ xcat0) {
  int idx = blockIdx.x * 256 + threadIdx.x;   // 128*1024
  int b = idx >> 10, d = idx & 1023;
  m[idx] = 0.f;
  xcat0[(size_t)b * 3072 + 1024 + d] = f2bf(meanf[idx]);  // mean_f + ctx(=0)
  xcat0[(size_t)b * 3072 + 2048 + d] = 0;                 // h = 0
}

__launch_bounds__(256)
__global__ void wn_kernel(const float* __restrict__ pred_v, const float* __restrict__ pred_g,
                          unsigned short* __restrict__ Wn) {
  int v = blockIdx.x, tid = threadIdx.x;
  const float* row = pred_v + (size_t)v * DD;
  float s = 0.f;
  for (int j = tid; j < DD; j += 256) { float x = row[j]; s += x * x; }
  #pragma unroll
  for (int o = 32; o; o >>= 1) s += __shfl_down(s, o);
  __shared__ float red[4];
  if ((tid & 63) == 0) red[tid >> 6] = s;
  __syncthreads();
  float inv = pred_g[v] * rsqrtf(red[0] + red[1] + red[2] + red[3]);
  for (int j = tid; j < DD; j += 256) Wn[(size_t)v * DD + j] = f2bf(row[j] * inv);
}

__launch_bounds__(256)
__global__ void emb_kernel(const float* __restrict__ embed_W, const int* __restrict__ captions,
                           unsigned short* __restrict__ xcat) {
  int idx = blockIdx.x * 256 + threadIdx.x;   // 20*128*1024
  int j = idx & 1023, b = (idx >> 10) & 127, t = idx >> 17;
  int tok = captions[b * TT + t];
  xcat[((size_t)t * BB + b) * 3072 + j] = f2bf(embed_W[(size_t)tok * DD + j]);
}

__launch_bounds__(256)
__global__ void lstm_kernel(const float* __restrict__ gates, float* __restrict__ m,
                            unsigned short* __restrict__ qin, unsigned short* __restrict__ xaoa,
                            unsigned short* __restrict__ xcat_next) {
  int idx = blockIdx.x * 256 + threadIdx.x;   // 128*1024
  int b = idx >> 10, d = idx & 1023;
  const float* g = gates + (size_t)b * 4096;
  float gi = g[d], gf = g[1024 + d], gg = g[2048 + d], go = g[3072 + d];
  float m2 = sigm(gf) * m[idx] + sigm(gi) * tanhf(gg);
  float h2 = sigm(go) * tanhf(m2);
  m[idx] = m2;
  unsigned short hb = f2bf(h2);
  qin[idx] = hb;
  xaoa[(size_t)b * 2048 + 1024 + d] = hb;
  xcat_next[(size_t)b * 3072 + 2048 + d] = hb;
}

__launch_bounds__(256)
__global__ void attn_kernel(const float* __restrict__ q, const unsigned short* __restrict__ Kb,
                            const unsigned short* __restrict__ Vb, unsigned short* __restrict__ xaoa) {
  int bh = blockIdx.x, b = bh >> 3, h = bh & 7;
  int tid = threadIdx.x;
  __shared__ float qs[DHH];
  __shared__ float sc[NN];
  if (tid < DHH) qs[tid] = q[(size_t)b * DD + h * DHH + tid];
  __syncthreads();
  if (tid < NN) {
    const unsigned short* kr = Kb + ((size_t)(b * NN + tid)) * DD + h * DHH;
    float a = 0.f;
    #pragma unroll 4
    for (int d = 0; d < DHH; ++d) a += qs[d] * bf2f(kr[d]);
    sc[tid] = a * 0.08838834764831845f;   // 1/sqrt(128)
  }
  __syncthreads();
  float mx = -1e30f;
  for (int n = 0; n < NN; ++n) mx = fmaxf(mx, sc[n]);
  float sm = 0.f;
  for (int n = 0; n < NN; ++n) sm += __expf(sc[n] - mx);
  if (tid < DHH) {
    const unsigned short* vr = Vb + ((size_t)(b * NN)) * DD + h * DHH + tid;
    float a = 0.f;
    for (int n = 0; n < NN; ++n) a += __expf(sc[n] - mx) * bf2f(vr[(size_t)n * DD]);
    a /= sm;
    xaoa[(size_t)b * 2048 + h * DHH + tid] = f2bf(a);
  }
}

__launch_bounds__(256)
__global__ void glu_kernel(const float* __restrict__ a, const float* __restrict__ meanf,
                           unsigned short* __restrict__ predin, unsigned short* __restrict__ xcat_next) {
  int idx = blockIdx.x * 256 + threadIdx.x;   // 128*1024
  int b = idx >> 10, d = idx & 1023;
  float a1 = a[(size_t)b * 2048 + d], a2 = a[(size_t)b * 2048 + 1024 + d];
  float c2 = a1 * sigm(a2);
  predin[idx] = f2bf(c2);
  xcat_next[(size_t)b * 3072 + 1024 + d] = f2bf(meanf[idx] + c2);
}

extern "C" void kernel_launch(void* const* d_in, const int* in_sizes, int n_in,
                              void* d_out, int out_size, void* d_ws, size_t ws_size,
                              hipStream_t stream) {
  const float* enc      = (const float*)d_in[0];
  const int*   captions = (const int*)d_in[1];
  const int*   lengths  = (const int*)d_in[2];
  const float* embed_W  = (const float*)d_in[3];
  const float* W_ih     = (const float*)d_in[4];
  const float* b_ih     = (const float*)d_in[5];
  const float* W_hh     = (const float*)d_in[6];
  const float* b_hh     = (const float*)d_in[7];
  const float* Wq       = (const float*)d_in[8];
  const float* bq       = (const float*)d_in[9];
  const float* Wk       = (const float*)d_in[10];
  const float* bk       = (const float*)d_in[11];
  const float* Wv       = (const float*)d_in[12];
  const float* bv       = (const float*)d_in[13];
  const float* W_aoa    = (const float*)d_in[14];
  const float* b_aoa    = (const float*)d_in[15];
  const float* pred_v   = (const float*)d_in[16];
  const float* pred_g   = (const float*)d_in[17];
  const float* pred_b   = (const float*)d_in[18];
  float* out = (float*)d_out;

  char* base = (char*)d_ws;
  size_t off = 0;
  auto alloc = [&](size_t bytes) -> char* {
    char* p = base + off;
    off = (off + bytes + 255) & ~(size_t)255;
    return p;
  };
  unsigned short* K_b    = (unsigned short*)alloc((size_t)BB * NN * DD * 2);
  unsigned short* V_b    = (unsigned short*)alloc((size_t)BB * NN * DD * 2);
  unsigned short* Wcat_b = (unsigned short*)alloc((size_t)4096 * 3072 * 2);
  unsigned short* Wn_b   = (unsigned short*)alloc((size_t)VV * DD * 2);
  unsigned short* Waoa_b = (unsigned short*)alloc((size_t)2048 * 2048 * 2);
  unsigned short* Wq_b   = (unsigned short*)alloc((size_t)DD * DD * 2);
  unsigned short* Wk_b   = (unsigned short*)alloc((size_t)DD * DD * 2);
  unsigned short* Wv_b   = (unsigned short*)alloc((size_t)DD * DD * 2);
  float* bcomb           = (float*)alloc(4096 * 4);
  float* meanf           = (float*)alloc((size_t)BB * DD * 4);
  float* mbuf            = (float*)alloc((size_t)BB * DD * 4);
  float* gates           = (float*)alloc((size_t)BB * 4096 * 4);
  float* qbuf            = (float*)alloc((size_t)BB * DD * 4);
  unsigned short* qin    = (unsigned short*)alloc((size_t)BB * DD * 2);
  unsigned short* xaoa   = (unsigned short*)alloc((size_t)BB * 2048 * 2);
  float* abuf            = (float*)alloc((size_t)BB * 2048 * 4);
  unsigned short* predin = (unsigned short*)alloc((size_t)BB * DD * 2);
  unsigned short* xcat   = (unsigned short*)alloc((size_t)21 * BB * 3072 * 2);
  if (off > ws_size) return;   // ws too small: diagnostic no-op (absmax == stub value)

  // ---- precompute ----
  mean_kernel<<<512, 256, 0, stream>>>(enc, meanf);
  init_kernel<<<512, 256, 0, stream>>>(meanf, mbuf, xcat);
  wcat_kernel<<<49152, 256, 0, stream>>>(W_ih, W_hh, Wcat_b);
  conv_kernel<<<4096, 256, 0, stream>>>(Wq, Wq_b, DD * DD);
  conv_kernel<<<4096, 256, 0, stream>>>(Wk, Wk_b, DD * DD);
  conv_kernel<<<4096, 256, 0, stream>>>(Wv, Wv_b, DD * DD);
  conv_kernel<<<16384, 256, 0, stream>>>(W_aoa, Waoa_b, 2048 * 2048);
  bcomb_kernel<<<16, 256, 0, stream>>>(b_ih, b_hh, bcomb);
  wn_kernel<<<VV, 256, 0, stream>>>(pred_v, pred_g, Wn_b);
  emb_kernel<<<10240, 256, 0, stream>>>(embed_W, captions, xcat);
  // K/V projections of enc_features (fp32 A converted in staging)
  gemm_bt<1, true><<<dim3(8, 196), 256, 0, stream>>>(enc, Wk_b, bk, nullptr, K_b, DD, DD, nullptr, 0);
  gemm_bt<1, true><<<dim3(8, 196), 256, 0, stream>>>(enc, Wv_b, bv, nullptr, V_b, DD, DD, nullptr, 0);

  // ---- 20 recurrent steps ----
  for (int t = 0; t < TT; ++t) {
    unsigned short* xc = xcat + (size_t)t * BB * 3072;
    unsigned short* xn = xcat + (size_t)(t + 1) * BB * 3072;
    gemm_bt<0, false><<<dim3(32, 1), 256, 0, stream>>>(xc, Wcat_b, bcomb, gates, nullptr, 4096, 3072, nullptr, 0);
    lstm_kernel<<<512, 256, 0, stream>>>(gates, mbuf, qin, xaoa, xn);
    gemm_bt<0, false><<<dim3(8, 1), 256, 0, stream>>>(qin, Wq_b, bq, qbuf, nullptr, 1024, 1024, nullptr, 0);
    attn_kernel<<<BB * NHH, 256, 0, stream>>>(qbuf, K_b, V_b, xaoa);
    gemm_bt<0, false><<<dim3(16, 1), 256, 0, stream>>>(xaoa, Waoa_b, b_aoa, abuf, nullptr, 2048, 2048, nullptr, 0);
    glu_kernel<<<512, 256, 0, stream>>>(abuf, meanf, predin, xn);
    gemm_bt<2, false><<<dim3(79, 1), 256, 0, stream>>>(predin, Wn_b, pred_b, out, nullptr, VV, DD, lengths, t);
  }
}

// Round 2
// 2495.293 us; speedup vs baseline: 2.2422x; 2.2422x over previous
//
#include <hip/hip_runtime.h>
#include <hip/hip_bf16.h>
#include <cstdint>

#define BB 128
#define TT 20
#define VV 10000
#define DD 1024
#define NHH 8
#define DHH 128
#define NN 196

typedef float f32x4 __attribute__((ext_vector_type(4)));
typedef __bf16 bf16x8 __attribute__((ext_vector_type(8)));
typedef unsigned int u32x4 __attribute__((ext_vector_type(4)));
typedef unsigned int u32x2 __attribute__((ext_vector_type(2)));

__device__ __forceinline__ unsigned short f2bf(float x) {
  unsigned u = __float_as_uint(x);
  u += 0x7FFFu + ((u >> 16) & 1u);
  return (unsigned short)(u >> 16);
}
__device__ __forceinline__ float bf2f(unsigned short h) {
  return __uint_as_float(((unsigned)h) << 16);
}
__device__ __forceinline__ float sigm(float x) { return 1.f / (1.f + __expf(-x)); }
__device__ __forceinline__ unsigned pk2(float lo, float hi) {
  return (unsigned)f2bf(lo) | ((unsigned)f2bf(hi) << 16);
}
// bijective chunked XCD swizzle (m204): contiguous logical-tile chunk per XCD
__device__ __forceinline__ int xcd_swz(int orig, int nb) {
  int q = nb >> 3, r = nb & 7;
  int x = orig & 7, i = orig >> 3;
  return (x < r ? x * (q + 1) : r * (q + 1) + (x - r) * q) + i;
}

// ---- KV projection GEMM: C[25088,2048](bf16) = enc[25088,1024](f32->bf16) @ Wkv[2048,1024]^T + bkv
// grid 1-D = 16 x 196, XCD-swizzled so the 16 col-tiles sharing an A row-tile stay on one XCD.
__launch_bounds__(256)
__global__ void gemm_kv(const float* __restrict__ A, const unsigned short* __restrict__ W,
                        const float* __restrict__ bias, unsigned short* __restrict__ C)
{
  __shared__ unsigned short As[128][40];
  __shared__ unsigned short Bs[128][40];
  const int wg = xcd_swz(blockIdx.x, gridDim.x);
  const int rowbase = (wg >> 4) * 128;
  const int colbase = (wg & 15) * 128;
  const int tid = threadIdx.x;
  const int lane = tid & 63, wv = tid >> 6;
  const int wm = (wv >> 1) * 64, wn = (wv & 1) * 64;
  const int lr = lane & 15, lk = (lane >> 4) * 8;

  f32x4 acc[4][4];
  const f32x4 zero = {0.f, 0.f, 0.f, 0.f};
  #pragma unroll
  for (int i = 0; i < 4; ++i)
    #pragma unroll
    for (int j = 0; j < 4; ++j) acc[i][j] = zero;

  for (int kt = 0; kt < 32; ++kt) {
    const int k0 = kt << 5;
    #pragma unroll
    for (int s = 0; s < 2; ++s) {
      const int c = tid * 2 + s;
      const int r = c >> 2, off2 = (c & 3) << 3;
      const float* ap = A + (size_t)(rowbase + r) * 1024 + k0 + off2;
      f32x4 f0 = *reinterpret_cast<const f32x4*>(ap);
      f32x4 f1 = *reinterpret_cast<const f32x4*>(ap + 4);
      u32x4 va = { pk2(f0[0], f0[1]), pk2(f0[2], f0[3]), pk2(f1[0], f1[1]), pk2(f1[2], f1[3]) };
      u32x4 vb = *reinterpret_cast<const u32x4*>(W + (size_t)(colbase + r) * 1024 + k0 + off2);
      *reinterpret_cast<u32x4*>(&As[r][off2]) = va;
      *reinterpret_cast<u32x4*>(&Bs[r][off2]) = vb;
    }
    __syncthreads();
    bf16x8 af[4], bfr[4];
    #pragma unroll
    for (int i = 0; i < 4; ++i) af[i] = *reinterpret_cast<const bf16x8*>(&As[wm + i * 16 + lr][lk]);
    #pragma unroll
    for (int j = 0; j < 4; ++j) bfr[j] = *reinterpret_cast<const bf16x8*>(&Bs[wn + j * 16 + lr][lk]);
    #pragma unroll
    for (int i = 0; i < 4; ++i)
      #pragma unroll
      for (int j = 0; j < 4; ++j)
        acc[i][j] = __builtin_amdgcn_mfma_f32_16x16x32_bf16(af[i], bfr[j], acc[i][j], 0, 0, 0);
    __syncthreads();
  }

  #pragma unroll
  for (int i = 0; i < 4; ++i) {
    const int growb = rowbase + wm + i * 16 + (lane >> 4) * 4;
    #pragma unroll
    for (int j = 0; j < 4; ++j) {
      const int gcol = colbase + wn + j * 16 + (lane & 15);
      const float bv = bias[gcol];
      #pragma unroll
      for (int r = 0; r < 4; ++r)
        C[(size_t)(growb + r) * 2048 + gcol] = f2bf(acc[i][j][r] + bv);
    }
  }
}

// ---- per-step GEMM: BM=128, BN=64, split-K. MODE 0: fp32 partials (no bias), split s -> Cf + s*128*N.
// MODE 2: vocab direct out w/ bias+mask (single split).
template<int MODE>
__launch_bounds__(256)
__global__ void gemm2(const unsigned short* __restrict__ A, int lda,
                      const unsigned short* __restrict__ W, int K,
                      const float* __restrict__ bias, float* __restrict__ Cf,
                      int N, int nx, int kps,
                      const int* __restrict__ lengths, int tstep)
{
  __shared__ unsigned short As[128][40];
  __shared__ unsigned short Bs[64][40];
  const int wg = xcd_swz(blockIdx.x, gridDim.x);
  const int xi = wg % nx, split = wg / nx;
  const int colbase = xi * 64;
  const int tid = threadIdx.x;
  const int lane = tid & 63, wv = tid >> 6;
  const int wrow = wv * 32;
  const int lr = lane & 15, lk = (lane >> 4) * 8;

  f32x4 acc[2][4];
  const f32x4 zero = {0.f, 0.f, 0.f, 0.f};
  #pragma unroll
  for (int i = 0; i < 2; ++i)
    #pragma unroll
    for (int j = 0; j < 4; ++j) acc[i][j] = zero;

  const int kt0 = split * kps;
  for (int kt = kt0; kt < kt0 + kps; ++kt) {
    const int k0 = kt << 5;
    #pragma unroll
    for (int s = 0; s < 2; ++s) {           // A: 512 chunks, 2/thread
      const int c = tid * 2 + s;
      const int r = c >> 2, off2 = (c & 3) << 3;
      *reinterpret_cast<u32x4*>(&As[r][off2]) =
        *reinterpret_cast<const u32x4*>(A + (size_t)r * lda + k0 + off2);
    }
    {                                        // B: 256 chunks, 1/thread
      const int r = tid >> 2, off2 = (tid & 3) << 3;
      int wr = colbase + r;
      if (MODE == 2) wr = wr < N ? wr : N - 1;
      *reinterpret_cast<u32x4*>(&Bs[r][off2]) =
        *reinterpret_cast<const u32x4*>(W + (size_t)wr * K + k0 + off2);
    }
    __syncthreads();
    bf16x8 af[2], bfr[4];
    af[0] = *reinterpret_cast<const bf16x8*>(&As[wrow + lr][lk]);
    af[1] = *reinterpret_cast<const bf16x8*>(&As[wrow + 16 + lr][lk]);
    #pragma unroll
    for (int j = 0; j < 4; ++j) bfr[j] = *reinterpret_cast<const bf16x8*>(&Bs[j * 16 + lr][lk]);
    #pragma unroll
    for (int i = 0; i < 2; ++i)
      #pragma unroll
      for (int j = 0; j < 4; ++j)
        acc[i][j] = __builtin_amdgcn_mfma_f32_16x16x32_bf16(af[i], bfr[j], acc[i][j], 0, 0, 0);
    __syncthreads();
  }

  #pragma unroll
  for (int i = 0; i < 2; ++i) {
    const int growb = wrow + i * 16 + (lane >> 4) * 4;
    #pragma unroll
    for (int j = 0; j < 4; ++j) {
      const int gcol = colbase + j * 16 + (lane & 15);
      if (MODE == 2) {
        if (gcol >= N) continue;
        const float bv = bias[gcol];
        #pragma unroll
        for (int r = 0; r < 4; ++r) {
          const int gr = growb + r;
          Cf[((size_t)gr * TT + tstep) * VV + gcol] =
              (tstep < lengths[gr]) ? acc[i][j][r] + bv : 0.f;
        }
      } else {
        float* dst = Cf + (size_t)split * 128 * N;
        #pragma unroll
        for (int r = 0; r < 4; ++r)
          dst[(size_t)(growb + r) * N + gcol] = acc[i][j][r];
      }
    }
  }
}

// ---- pointwise / prep kernels ----
__launch_bounds__(256)
__global__ void conv4_kernel(const float* __restrict__ src, unsigned short* __restrict__ dst) {
  int i = blockIdx.x * 256 + threadIdx.x;
  f32x4 v = *reinterpret_cast<const f32x4*>(src + (size_t)i * 4);
  u32x2 o = { pk2(v[0], v[1]), pk2(v[2], v[3]) };
  *reinterpret_cast<u32x2*>(dst + (size_t)i * 4) = o;
}

__launch_bounds__(256)
__global__ void wcat4_kernel(const float* __restrict__ W_ih, const float* __restrict__ W_hh,
                             unsigned short* __restrict__ Wcat) {
  int i = blockIdx.x * 256 + threadIdx.x;     // 4096*768 vec4 chunks
  int row = i / 768, c4 = (i - row * 768) * 4;
  const float* src = (c4 < 2048) ? (W_ih + (size_t)row * 2048 + c4)
                                 : (W_hh + (size_t)row * 1024 + (c4 - 2048));
  f32x4 v = *reinterpret_cast<const f32x4*>(src);
  u32x2 o = { pk2(v[0], v[1]), pk2(v[2], v[3]) };
  *reinterpret_cast<u32x2*>(Wcat + (size_t)row * 3072 + c4) = o;
}

__launch_bounds__(256)
__global__ void kvw4_kernel(const float* __restrict__ Wk, const float* __restrict__ Wv,
                            unsigned short* __restrict__ Wkv) {
  int i = blockIdx.x * 256 + threadIdx.x;     // 2048*256 vec4 chunks
  int row = i >> 8, c4 = (i & 255) << 2;
  const float* src = (row < 1024) ? (Wk + (size_t)row * 1024 + c4)
                                  : (Wv + (size_t)(row - 1024) * 1024 + c4);
  f32x4 v = *reinterpret_cast<const f32x4*>(src);
  u32x2 o = { pk2(v[0], v[1]), pk2(v[2], v[3]) };
  *reinterpret_cast<u32x2*>(Wkv + (size_t)row * 1024 + c4) = o;
}

__launch_bounds__(256)
__global__ void bkv_kernel(const float* __restrict__ bk, const float* __restrict__ bv,
                           float* __restrict__ bkv) {
  int i = blockIdx.x * 256 + threadIdx.x;
  if (i < 2048) bkv[i] = (i < 1024) ? bk[i] : bv[i - 1024];
}

__launch_bounds__(256)
__global__ void mean_kernel(const float* __restrict__ enc, float* __restrict__ meanf) {
  int idx = blockIdx.x * 256 + threadIdx.x;   // 128*1024
  int b = idx >> 10, d = idx & 1023;
  const float* p = enc + (size_t)b * NN * DD + d;
  float s = 0.f;
  for (int n = 0; n < NN; ++n) s += p[(size_t)n * DD];
  meanf[idx] = s * (1.0f / (float)NN);
}

__launch_bounds__(256)
__global__ void init_kernel(const float* __restrict__ meanf, float* __restrict__ m,
                            unsigned short* __restrict__ xcat0) {
  int idx = blockIdx.x * 256 + threadIdx.x;   // 128*1024
  int b = idx >> 10, d = idx & 1023;
  m[idx] = 0.f;
  xcat0[(size_t)b * 3072 + 1024 + d] = f2bf(meanf[idx]);
  xcat0[(size_t)b * 3072 + 2048 + d] = 0;
}

__launch_bounds__(256)
__global__ void wn_kernel(const float* __restrict__ pred_v, const float* __restrict__ pred_g,
                          unsigned short* __restrict__ Wn) {
  int v = blockIdx.x, tid = threadIdx.x;
  const float* row = pred_v + (size_t)v * DD;
  float s = 0.f;
  for (int j = tid; j < DD; j += 256) { float x = row[j]; s += x * x; }
  #pragma unroll
  for (int o = 32; o; o >>= 1) s += __shfl_down(s, o);
  __shared__ float red[4];
  if ((tid & 63) == 0) red[tid >> 6] = s;
  __syncthreads();
  float inv = pred_g[v] * rsqrtf(red[0] + red[1] + red[2] + red[3]);
  for (int j = tid; j < DD; j += 256) Wn[(size_t)v * DD + j] = f2bf(row[j] * inv);
}

__launch_bounds__(256)
__global__ void emb4_kernel(const float* __restrict__ embed_W, const int* __restrict__ captions,
                            unsigned short* __restrict__ xcat) {
  int i = blockIdx.x * 256 + threadIdx.x;     // 20*128*256 vec4 chunks
  int j4 = (i & 255) << 2, b = (i >> 8) & 127, t = i >> 15;
  int tok = captions[b * TT + t];
  f32x4 v = *reinterpret_cast<const f32x4*>(embed_W + (size_t)tok * DD + j4);
  u32x2 o = { pk2(v[0], v[1]), pk2(v[2], v[3]) };
  *reinterpret_cast<u32x2*>(xcat + ((size_t)t * BB + b) * 3072 + j4) = o;
}

__launch_bounds__(256)
__global__ void lstm_kernel(const float* __restrict__ gates, const float* __restrict__ b_ih,
                            const float* __restrict__ b_hh, float* __restrict__ m,
                            unsigned short* __restrict__ xaoa, unsigned short* __restrict__ xcat_next) {
  int idx = blockIdx.x * 256 + threadIdx.x;   // 128*1024
  int b = idx >> 10, d = idx & 1023;
  float gi = b_ih[d] + b_hh[d];
  float gf = b_ih[1024 + d] + b_hh[1024 + d];
  float gg = b_ih[2048 + d] + b_hh[2048 + d];
  float go = b_ih[3072 + d] + b_hh[3072 + d];
  #pragma unroll
  for (int sp = 0; sp < 4; ++sp) {
    const float* g = gates + (size_t)sp * BB * 4096 + (size_t)b * 4096;
    gi += g[d]; gf += g[1024 + d]; gg += g[2048 + d]; go += g[3072 + d];
  }
  float m2 = sigm(gf) * m[idx] + sigm(gi) * tanhf(gg);
  float h2 = sigm(go) * tanhf(m2);
  m[idx] = m2;
  unsigned short hb = f2bf(h2);
  xaoa[(size_t)b * 2048 + 1024 + d] = hb;
  xcat_next[(size_t)b * 3072 + 2048 + d] = hb;
}

__launch_bounds__(256)
__global__ void attn_kernel(const float* __restrict__ qbuf, const float* __restrict__ bq,
                            const unsigned short* __restrict__ KV, unsigned short* __restrict__ xaoa) {
  const int bh = blockIdx.x, b = bh >> 3, h = bh & 7;
  const int tid = threadIdx.x;
  __shared__ float qs[DHH];
  __shared__ float sc[NN];
  __shared__ float pvred[2][DHH];
  if (tid < DHH) {
    float s = bq[h * DHH + tid];
    #pragma unroll
    for (int sp = 0; sp < 4; ++sp)
      s += qbuf[(size_t)sp * BB * DD + (size_t)b * DD + h * DHH + tid];
    qs[tid] = s;
  }
  __syncthreads();
  if (tid < NN) {
    const unsigned short* kr = KV + ((size_t)(b * NN + tid)) * 2048 + h * DHH;
    float a = 0.f;
    #pragma unroll
    for (int j = 0; j < 16; ++j) {
      u32x4 kk = *reinterpret_cast<const u32x4*>(kr + j * 8);
      #pragma unroll
      for (int w = 0; w < 4; ++w) {
        a += bf2f((unsigned short)(kk[w] & 0xffffu)) * qs[j * 8 + w * 2]
           + bf2f((unsigned short)(kk[w] >> 16)) * qs[j * 8 + w * 2 + 1];
      }
    }
    sc[tid] = a * 0.08838834764831845f;   // 1/sqrt(128)
  }
  __syncthreads();
  float mx = -1e30f;
  for (int n = 0; n < NN; ++n) mx = fmaxf(mx, sc[n]);
  __syncthreads();
  if (tid < NN) sc[tid] = __expf(sc[tid] - mx);
  __syncthreads();
  float sm = 0.f;
  for (int n = 0; n < NN; ++n) sm += sc[n];
  const float inv = 1.f / sm;
  const int d = tid & 127, half = tid >> 7;
  const unsigned short* vr = KV + ((size_t)(b * NN + half * 98)) * 2048 + 1024 + h * DHH + d;
  float a = 0.f;
  for (int n = 0; n < 98; ++n) a += sc[half * 98 + n] * bf2f(vr[(size_t)n * 2048]);
  pvred[half][d] = a;
  __syncthreads();
  if (tid < DHH)
    xaoa[(size_t)b * 2048 + h * DHH + tid] = f2bf((pvred[0][tid] + pvred[1][tid]) * inv);
}

__launch_bounds__(256)
__global__ void glu_kernel(const float* __restrict__ abuf, const float* __restrict__ b_aoa,
                           const float* __restrict__ meanf,
                           unsigned short* __restrict__ predin, unsigned short* __restrict__ xcat_next) {
  int idx = blockIdx.x * 256 + threadIdx.x;   // 128*1024
  int b = idx >> 10, d = idx & 1023;
  float a1 = b_aoa[d], a2 = b_aoa[1024 + d];
  #pragma unroll
  for (int sp = 0; sp < 4; ++sp) {
    const float* a = abuf + (size_t)sp * BB * 2048 + (size_t)b * 2048;
    a1 += a[d]; a2 += a[1024 + d];
  }
  float c2 = a1 * sigm(a2);
  predin[idx] = f2bf(c2);
  xcat_next[(size_t)b * 3072 + 1024 + d] = f2bf(meanf[idx] + c2);
}

extern "C" void kernel_launch(void* const* d_in, const int* in_sizes, int n_in,
                              void* d_out, int out_size, void* d_ws, size_t ws_size,
                              hipStream_t stream) {
  const float* enc      = (const float*)d_in[0];
  const int*   captions = (const int*)d_in[1];
  const int*   lengths  = (const int*)d_in[2];
  const float* embed_W  = (const float*)d_in[3];
  const float* W_ih     = (const float*)d_in[4];
  const float* b_ih     = (const float*)d_in[5];
  const float* W_hh     = (const float*)d_in[6];
  const float* b_hh     = (const float*)d_in[7];
  const float* Wq       = (const float*)d_in[8];
  const float* bq       = (const float*)d_in[9];
  const float* Wk       = (const float*)d_in[10];
  const float* bk       = (const float*)d_in[11];
  const float* Wv       = (const float*)d_in[12];
  const float* bv       = (const float*)d_in[13];
  const float* W_aoa    = (const float*)d_in[14];
  const float* b_aoa    = (const float*)d_in[15];
  const float* pred_v   = (const float*)d_in[16];
  const float* pred_g   = (const float*)d_in[17];
  const float* pred_b   = (const float*)d_in[18];
  float* out = (float*)d_out;

  char* base = (char*)d_ws;
  size_t off = 0;
  auto alloc = [&](size_t bytes) -> char* {
    char* p = base + off;
    off = (off + bytes + 255) & ~(size_t)255;
    return p;
  };
  unsigned short* KV     = (unsigned short*)alloc((size_t)BB * NN * 2048 * 2);
  unsigned short* Wcat_b = (unsigned short*)alloc((size_t)4096 * 3072 * 2);
  unsigned short* Wn_b   = (unsigned short*)alloc((size_t)VV * DD * 2);
  unsigned short* Waoa_b = (unsigned short*)alloc((size_t)2048 * 2048 * 2);
  unsigned short* Wq_b   = (unsigned short*)alloc((size_t)DD * DD * 2);
  unsigned short* Wkv_b  = (unsigned short*)alloc((size_t)2048 * 1024 * 2);
  float* bkv             = (float*)alloc(2048 * 4);
  float* meanf           = (float*)alloc((size_t)BB * DD * 4);
  float* mbuf            = (float*)alloc((size_t)BB * DD * 4);
  float* gates           = (float*)alloc((size_t)4 * BB * 4096 * 4);
  float* qbuf            = (float*)alloc((size_t)4 * BB * DD * 4);
  unsigned short* xaoa   = (unsigned short*)alloc((size_t)BB * 2048 * 2);
  float* abuf            = (float*)alloc((size_t)4 * BB * 2048 * 4);
  unsigned short* predin = (unsigned short*)alloc((size_t)BB * DD * 2);
  unsigned short* xcat   = (unsigned short*)alloc((size_t)21 * BB * 3072 * 2);
  if (off > ws_size) return;   // ws too small: diagnostic no-op

  // ---- precompute ----
  mean_kernel<<<512, 256, 0, stream>>>(enc, meanf);
  init_kernel<<<512, 256, 0, stream>>>(meanf, mbuf, xcat);
  wcat4_kernel<<<12288, 256, 0, stream>>>(W_ih, W_hh, Wcat_b);
  conv4_kernel<<<1024, 256, 0, stream>>>(Wq, Wq_b);
  conv4_kernel<<<4096, 256, 0, stream>>>(W_aoa, Waoa_b);
  kvw4_kernel<<<2048, 256, 0, stream>>>(Wk, Wv, Wkv_b);
  bkv_kernel<<<8, 256, 0, stream>>>(bk, bv, bkv);
  wn_kernel<<<VV, 256, 0, stream>>>(pred_v, pred_g, Wn_b);
  emb4_kernel<<<2560, 256, 0, stream>>>(embed_W, captions, xcat);
  gemm_kv<<<16 * 196, 256, 0, stream>>>(enc, Wkv_b, bkv, KV);

  // ---- 20 recurrent steps ----
  for (int t = 0; t < TT; ++t) {
    unsigned short* xc = xcat + (size_t)t * BB * 3072;
    unsigned short* xn = xcat + (size_t)(t + 1) * BB * 3072;
    // gates: K=3072 (96 kt), nx=64, 4 splits x 24 kt
    gemm2<0><<<256, 256, 0, stream>>>(xc, 3072, Wcat_b, 3072, nullptr, gates, 4096, 64, 24, nullptr, 0);
    lstm_kernel<<<512, 256, 0, stream>>>(gates, b_ih, b_hh, mbuf, xaoa, xn);
    // q: A = h2 slice of xaoa (lda 2048), K=1024 (32 kt), nx=16, 4 splits x 8 kt
    gemm2<0><<<64, 256, 0, stream>>>(xaoa + 1024, 2048, Wq_b, 1024, nullptr, qbuf, 1024, 16, 8, nullptr, 0);
    attn_kernel<<<BB * NHH, 256, 0, stream>>>(qbuf, bq, KV, xaoa);
    // aoa: K=2048 (64 kt), nx=32, 4 splits x 16 kt
    gemm2<0><<<128, 256, 0, stream>>>(xaoa, 2048, Waoa_b, 2048, nullptr, abuf, 2048, 32, 16, nullptr, 0);
    glu_kernel<<<512, 256, 0, stream>>>(abuf, b_aoa, meanf, predin, xn);
    // vocab: K=1024 (32 kt), nx=157, single split
    gemm2<2><<<157, 256, 0, stream>>>(predin, 1024, Wn_b, 1024, pred_b, out, VV, 157, 32, lengths, t);
  }
}

// Round 3
// 2092.980 us; speedup vs baseline: 2.6732x; 1.1922x over previous
//
#include <hip/hip_runtime.h>
#include <hip/hip_bf16.h>
#include <cstdint>

#define BB 128
#define TT 20
#define VV 10000
#define DD 1024
#define NHH 8
#define DHH 128
#define NN 196

typedef float f32x4 __attribute__((ext_vector_type(4)));
typedef __bf16 bf16x8 __attribute__((ext_vector_type(8)));
typedef unsigned int u32x4 __attribute__((ext_vector_type(4)));
typedef unsigned int u32x2 __attribute__((ext_vector_type(2)));

__device__ __forceinline__ unsigned short f2bf(float x) {
  unsigned u = __float_as_uint(x);
  u += 0x7FFFu + ((u >> 16) & 1u);
  return (unsigned short)(u >> 16);
}
__device__ __forceinline__ float bf2f(unsigned short h) {
  return __uint_as_float(((unsigned)h) << 16);
}
__device__ __forceinline__ float sigm(float x) { return 1.f / (1.f + __expf(-x)); }
__device__ __forceinline__ unsigned pk2(float lo, float hi) {
  return (unsigned)f2bf(lo) | ((unsigned)f2bf(hi) << 16);
}
// bijective chunked XCD swizzle (m204)
__device__ __forceinline__ int xcd_swz(int orig, int nb) {
  int q = nb >> 3, r = nb & 7;
  int x = orig & 7, i = orig >> 3;
  return (x < r ? x * (q + 1) : r * (q + 1) + (x - r) * q) + i;
}
// async global->LDS, 16B/lane (LDS dest wave-uniform base, lane*16 stride)
__device__ __forceinline__ void gl16(const void* g, void* l) {
  __builtin_amdgcn_global_load_lds((const __attribute__((address_space(1))) void*)g,
                                   (__attribute__((address_space(3))) void*)l, 16, 0, 0);
}

// ---- KV projection GEMM (m97 structure): C[25088,2048](bf16) = encb[25088,1024] @ Wkv[2048,1024]^T + bkv
__launch_bounds__(256)
__global__ void gemm_kv(const unsigned short* __restrict__ A, const unsigned short* __restrict__ W,
                        const float* __restrict__ bias, unsigned short* __restrict__ C)
{
  __shared__ unsigned short As[128][32];
  __shared__ unsigned short Bs[128][32];
  const int wg = xcd_swz(blockIdx.x, gridDim.x);
  const int rowbase = (wg >> 4) * 128;
  const int colbase = (wg & 15) * 128;
  const int tid = threadIdx.x;
  const int lane = tid & 63, wv = tid >> 6;
  const int wm = (wv >> 1) * 64, wn = (wv & 1) * 64;
  const int lr = lane & 15, lk = (lane >> 4) * 8;

  // staging addresses: issue s covers rows s*64 + wv*16 + (lane>>2), 16B chunk (lane&3)
  const int srow = wv * 16 + (lane >> 2);
  const int schunk = (lane & 3) * 8;
  const unsigned short* a0 = A + (size_t)(rowbase + srow) * 1024 + schunk;
  const unsigned short* a1 = A + (size_t)(rowbase + 64 + srow) * 1024 + schunk;
  const unsigned short* b0 = W + (size_t)(colbase + srow) * 1024 + schunk;
  const unsigned short* b1 = W + (size_t)(colbase + 64 + srow) * 1024 + schunk;
  unsigned short* lA0 = &As[wv * 16][0];
  unsigned short* lA1 = &As[64 + wv * 16][0];
  unsigned short* lB0 = &Bs[wv * 16][0];
  unsigned short* lB1 = &Bs[64 + wv * 16][0];

  f32x4 acc[4][4];
  const f32x4 zero = {0.f, 0.f, 0.f, 0.f};
  #pragma unroll
  for (int i = 0; i < 4; ++i)
    #pragma unroll
    for (int j = 0; j < 4; ++j) acc[i][j] = zero;

  for (int kt = 0; kt < 32; ++kt) {
    const int k0 = kt << 5;
    gl16(a0 + k0, lA0); gl16(a1 + k0, lA1);
    gl16(b0 + k0, lB0); gl16(b1 + k0, lB1);
    __syncthreads();
    bf16x8 af[4], bfr[4];
    #pragma unroll
    for (int i = 0; i < 4; ++i) af[i] = *reinterpret_cast<const bf16x8*>(&As[wm + i * 16 + lr][lk]);
    #pragma unroll
    for (int j = 0; j < 4; ++j) bfr[j] = *reinterpret_cast<const bf16x8*>(&Bs[wn + j * 16 + lr][lk]);
    #pragma unroll
    for (int i = 0; i < 4; ++i)
      #pragma unroll
      for (int j = 0; j < 4; ++j)
        acc[i][j] = __builtin_amdgcn_mfma_f32_16x16x32_bf16(af[i], bfr[j], acc[i][j], 0, 0, 0);
    __syncthreads();
  }

  #pragma unroll
  for (int i = 0; i < 4; ++i) {
    const int growb = rowbase + wm + i * 16 + (lane >> 4) * 4;
    #pragma unroll
    for (int j = 0; j < 4; ++j) {
      const int gcol = colbase + wn + j * 16 + (lane & 15);
      const float bv = bias[gcol];
      #pragma unroll
      for (int r = 0; r < 4; ++r)
        C[(size_t)(growb + r) * 2048 + gcol] = f2bf(acc[i][j][r] + bv);
    }
  }
}

// ---- per-step GEMM: BM=128, BN=64, split-K, 2-phase dbuf + global_load_lds.
// MODE 0: fp32 partials (split s -> Cf + s*128*N).  MODE 2: vocab direct out w/ bias+mask.
template<int MODE>
__launch_bounds__(256)
__global__ void gemm2(const unsigned short* __restrict__ A, int lda,
                      const unsigned short* __restrict__ W, int K,
                      const float* __restrict__ bias, float* __restrict__ Cf,
                      int N, int nx, int kps,
                      const int* __restrict__ lengths, int tstep)
{
  __shared__ unsigned short As[2][128][32];
  __shared__ unsigned short Bs[2][64][32];
  const int wg = xcd_swz(blockIdx.x, gridDim.x);
  const int xi = wg % nx, split = wg / nx;
  const int colbase = xi * 64;
  const int tid = threadIdx.x;
  const int lane = tid & 63, wv = tid >> 6;
  const int wrow = wv * 32;
  const int lr = lane & 15, lk = (lane >> 4) * 8;

  const int srow = wv * 16 + (lane >> 2);
  const int schunk = (lane & 3) * 8;
  const unsigned short* a0 = A + (size_t)srow * lda + schunk;
  const unsigned short* a1 = A + (size_t)(64 + srow) * lda + schunk;
  int brow = colbase + srow;
  if (MODE == 2) brow = brow < N ? brow : N - 1;
  const unsigned short* b0 = W + (size_t)brow * K + schunk;

  f32x4 acc[2][4];
  const f32x4 zero = {0.f, 0.f, 0.f, 0.f};
  #pragma unroll
  for (int i = 0; i < 2; ++i)
    #pragma unroll
    for (int j = 0; j < 4; ++j) acc[i][j] = zero;

  const int kt0 = split * kps;
  // prologue: stage tile 0 into buf 0
  {
    const int k0 = kt0 << 5;
    gl16(a0 + k0, &As[0][wv * 16][0]);
    gl16(a1 + k0, &As[0][64 + wv * 16][0]);
    gl16(b0 + k0, &Bs[0][wv * 16][0]);
  }
  __syncthreads();
  int cur = 0;
  for (int i = 0; i < kps; ++i) {
    if (i + 1 < kps) {                       // stage next tile into other buffer
      const int k0 = (kt0 + i + 1) << 5;
      gl16(a0 + k0, &As[cur ^ 1][wv * 16][0]);
      gl16(a1 + k0, &As[cur ^ 1][64 + wv * 16][0]);
      gl16(b0 + k0, &Bs[cur ^ 1][wv * 16][0]);
    }
    bf16x8 af[2], bfr[4];
    af[0] = *reinterpret_cast<const bf16x8*>(&As[cur][wrow + lr][lk]);
    af[1] = *reinterpret_cast<const bf16x8*>(&As[cur][wrow + 16 + lr][lk]);
    #pragma unroll
    for (int j = 0; j < 4; ++j) bfr[j] = *reinterpret_cast<const bf16x8*>(&Bs[cur][j * 16 + lr][lk]);
    #pragma unroll
    for (int ii = 0; ii < 2; ++ii)
      #pragma unroll
      for (int j = 0; j < 4; ++j)
        acc[ii][j] = __builtin_amdgcn_mfma_f32_16x16x32_bf16(af[ii], bfr[j], acc[ii][j], 0, 0, 0);
    __syncthreads();                          // drains vmcnt (next tile staged) + lgkm
    cur ^= 1;
  }

  #pragma unroll
  for (int i = 0; i < 2; ++i) {
    const int growb = wrow + i * 16 + (lane >> 4) * 4;
    #pragma unroll
    for (int j = 0; j < 4; ++j) {
      const int gcol = colbase + j * 16 + (lane & 15);
      if (MODE == 2) {
        if (gcol >= N) continue;
        const float bv = bias[gcol];
        #pragma unroll
        for (int r = 0; r < 4; ++r) {
          const int gr = growb + r;
          Cf[((size_t)gr * TT + tstep) * VV + gcol] =
              (tstep < lengths[gr]) ? acc[i][j][r] + bv : 0.f;
        }
      } else {
        float* dst = Cf + (size_t)split * 128 * N;
        #pragma unroll
        for (int r = 0; r < 4; ++r)
          dst[(size_t)(growb + r) * N + gcol] = acc[i][j][r];
      }
    }
  }
}

// ---- pointwise / prep kernels ----
__launch_bounds__(256)
__global__ void meanconv_kernel(const float* __restrict__ enc, float* __restrict__ meanf,
                                unsigned short* __restrict__ encb) {
  // grid 128*4: block = (b, 256-wide d-group). Fuses mean over N with fp32->bf16 convert.
  int b = blockIdx.x >> 2, d = (blockIdx.x & 3) * 256 + threadIdx.x;
  const float* p = enc + (size_t)b * NN * DD + d;
  unsigned short* q = encb + (size_t)b * NN * DD + d;
  float s = 0.f;
  for (int n = 0; n < NN; ++n) {
    float x = p[(size_t)n * DD];
    s += x;
    q[(size_t)n * DD] = f2bf(x);
  }
  meanf[(size_t)b * DD + d] = s * (1.0f / (float)NN);
}

__launch_bounds__(256)
__global__ void conv4_kernel(const float* __restrict__ src, unsigned short* __restrict__ dst) {
  int i = blockIdx.x * 256 + threadIdx.x;
  f32x4 v = *reinterpret_cast<const f32x4*>(src + (size_t)i * 4);
  u32x2 o = { pk2(v[0], v[1]), pk2(v[2], v[3]) };
  *reinterpret_cast<u32x2*>(dst + (size_t)i * 4) = o;
}

__launch_bounds__(256)
__global__ void wcat4_kernel(const float* __restrict__ W_ih, const float* __restrict__ W_hh,
                             unsigned short* __restrict__ Wcat) {
  int i = blockIdx.x * 256 + threadIdx.x;     // 4096*768 vec4 chunks
  int row = i / 768, c4 = (i - row * 768) * 4;
  const float* src = (c4 < 2048) ? (W_ih + (size_t)row * 2048 + c4)
                                 : (W_hh + (size_t)row * 1024 + (c4 - 2048));
  f32x4 v = *reinterpret_cast<const f32x4*>(src);
  u32x2 o = { pk2(v[0], v[1]), pk2(v[2], v[3]) };
  *reinterpret_cast<u32x2*>(Wcat + (size_t)row * 3072 + c4) = o;
}

__launch_bounds__(256)
__global__ void kvw4_kernel(const float* __restrict__ Wk, const float* __restrict__ Wv,
                            unsigned short* __restrict__ Wkv) {
  int i = blockIdx.x * 256 + threadIdx.x;     // 2048*256 vec4 chunks
  int row = i >> 8, c4 = (i & 255) << 2;
  const float* src = (row < 1024) ? (Wk + (size_t)row * 1024 + c4)
                                  : (Wv + (size_t)(row - 1024) * 1024 + c4);
  f32x4 v = *reinterpret_cast<const f32x4*>(src);
  u32x2 o = { pk2(v[0], v[1]), pk2(v[2], v[3]) };
  *reinterpret_cast<u32x2*>(Wkv + (size_t)row * 1024 + c4) = o;
}

__launch_bounds__(256)
__global__ void bkv_kernel(const float* __restrict__ bk, const float* __restrict__ bv,
                           float* __restrict__ bkv) {
  int i = blockIdx.x * 256 + threadIdx.x;
  if (i < 2048) bkv[i] = (i < 1024) ? bk[i] : bv[i - 1024];
}

__launch_bounds__(256)
__global__ void init_kernel(const float* __restrict__ meanf, float* __restrict__ m,
                            unsigned short* __restrict__ xcat0) {
  int idx = blockIdx.x * 256 + threadIdx.x;   // 128*1024
  int b = idx >> 10, d = idx & 1023;
  m[idx] = 0.f;
  xcat0[(size_t)b * 3072 + 1024 + d] = f2bf(meanf[idx]);
  xcat0[(size_t)b * 3072 + 2048 + d] = 0;
}

__launch_bounds__(256)
__global__ void wn_kernel(const float* __restrict__ pred_v, const float* __restrict__ pred_g,
                          unsigned short* __restrict__ Wn) {
  int v = blockIdx.x, tid = threadIdx.x;
  const float* row = pred_v + (size_t)v * DD;
  float s = 0.f;
  for (int j = tid; j < DD; j += 256) { float x = row[j]; s += x * x; }
  #pragma unroll
  for (int o = 32; o; o >>= 1) s += __shfl_down(s, o);
  __shared__ float red[4];
  if ((tid & 63) == 0) red[tid >> 6] = s;
  __syncthreads();
  float inv = pred_g[v] * rsqrtf(red[0] + red[1] + red[2] + red[3]);
  for (int j = tid; j < DD; j += 256) Wn[(size_t)v * DD + j] = f2bf(row[j] * inv);
}

__launch_bounds__(256)
__global__ void emb4_kernel(const float* __restrict__ embed_W, const int* __restrict__ captions,
                            unsigned short* __restrict__ xcat) {
  int i = blockIdx.x * 256 + threadIdx.x;     // 20*128*256 vec4 chunks
  int j4 = (i & 255) << 2, b = (i >> 8) & 127, t = i >> 15;
  int tok = captions[b * TT + t];
  f32x4 v = *reinterpret_cast<const f32x4*>(embed_W + (size_t)tok * DD + j4);
  u32x2 o = { pk2(v[0], v[1]), pk2(v[2], v[3]) };
  *reinterpret_cast<u32x2*>(xcat + ((size_t)t * BB + b) * 3072 + j4) = o;
}

__launch_bounds__(256)
__global__ void lstm_kernel(const float* __restrict__ gates, const float* __restrict__ b_ih,
                            const float* __restrict__ b_hh, float* __restrict__ m,
                            unsigned short* __restrict__ xaoa, unsigned short* __restrict__ xcat_next) {
  int idx = blockIdx.x * 256 + threadIdx.x;   // 128*1024
  int b = idx >> 10, d = idx & 1023;
  float gi = b_ih[d] + b_hh[d];
  float gf = b_ih[1024 + d] + b_hh[1024 + d];
  float gg = b_ih[2048 + d] + b_hh[2048 + d];
  float go = b_ih[3072 + d] + b_hh[3072 + d];
  #pragma unroll
  for (int sp = 0; sp < 4; ++sp) {
    const float* g = gates + (size_t)sp * BB * 4096 + (size_t)b * 4096;
    gi += g[d]; gf += g[1024 + d]; gg += g[2048 + d]; go += g[3072 + d];
  }
  float m2 = sigm(gf) * m[idx] + sigm(gi) * tanhf(gg);
  float h2 = sigm(go) * tanhf(m2);
  m[idx] = m2;
  unsigned short hb = f2bf(h2);
  xaoa[(size_t)b * 2048 + 1024 + d] = hb;
  xcat_next[(size_t)b * 3072 + 2048 + d] = hb;
}

__launch_bounds__(256)
__global__ void attn_kernel(const float* __restrict__ qbuf, const float* __restrict__ bq,
                            const unsigned short* __restrict__ KV, unsigned short* __restrict__ xaoa) {
  const int bh = blockIdx.x, b = bh >> 3, h = bh & 7;
  const int tid = threadIdx.x;
  __shared__ float qs[DHH];
  __shared__ float sc[NN];
  __shared__ float pvred[2][DHH];
  if (tid < DHH) {
    float s = bq[h * DHH + tid];
    #pragma unroll
    for (int sp = 0; sp < 8; ++sp)
      s += qbuf[(size_t)sp * BB * DD + (size_t)b * DD + h * DHH + tid];
    qs[tid] = s;
  }
  __syncthreads();
  if (tid < NN) {
    const unsigned short* kr = KV + ((size_t)(b * NN + tid)) * 2048 + h * DHH;
    float a = 0.f;
    #pragma unroll
    for (int j = 0; j < 16; ++j) {
      u32x4 kk = *reinterpret_cast<const u32x4*>(kr + j * 8);
      #pragma unroll
      for (int w = 0; w < 4; ++w) {
        a += bf2f((unsigned short)(kk[w] & 0xffffu)) * qs[j * 8 + w * 2]
           + bf2f((unsigned short)(kk[w] >> 16)) * qs[j * 8 + w * 2 + 1];
      }
    }
    sc[tid] = a * 0.08838834764831845f;   // 1/sqrt(128)
  }
  __syncthreads();
  float mx = -1e30f;
  for (int n = 0; n < NN; ++n) mx = fmaxf(mx, sc[n]);
  __syncthreads();
  if (tid < NN) sc[tid] = __expf(sc[tid] - mx);
  __syncthreads();
  float sm = 0.f;
  for (int n = 0; n < NN; ++n) sm += sc[n];
  const float inv = 1.f / sm;
  const int d = tid & 127, half = tid >> 7;
  const unsigned short* vr = KV + ((size_t)(b * NN + half * 98)) * 2048 + 1024 + h * DHH + d;
  float a = 0.f;
  for (int n = 0; n < 98; ++n) a += sc[half * 98 + n] * bf2f(vr[(size_t)n * 2048]);
  pvred[half][d] = a;
  __syncthreads();
  if (tid < DHH)
    xaoa[(size_t)b * 2048 + h * DHH + tid] = f2bf((pvred[0][tid] + pvred[1][tid]) * inv);
}

__launch_bounds__(256)
__global__ void glu_kernel(const float* __restrict__ abuf, const float* __restrict__ b_aoa,
                           const float* __restrict__ meanf,
                           unsigned short* __restrict__ predin, unsigned short* __restrict__ xcat_next) {
  int idx = blockIdx.x * 256 + threadIdx.x;   // 128*1024
  int b = idx >> 10, d = idx & 1023;
  float a1 = b_aoa[d], a2 = b_aoa[1024 + d];
  #pragma unroll
  for (int sp = 0; sp < 8; ++sp) {
    const float* a = abuf + (size_t)sp * BB * 2048 + (size_t)b * 2048;
    a1 += a[d]; a2 += a[1024 + d];
  }
  float c2 = a1 * sigm(a2);
  predin[idx] = f2bf(c2);
  xcat_next[(size_t)b * 3072 + 1024 + d] = f2bf(meanf[idx] + c2);
}

extern "C" void kernel_launch(void* const* d_in, const int* in_sizes, int n_in,
                              void* d_out, int out_size, void* d_ws, size_t ws_size,
                              hipStream_t stream) {
  const float* enc      = (const float*)d_in[0];
  const int*   captions = (const int*)d_in[1];
  const int*   lengths  = (const int*)d_in[2];
  const float* embed_W  = (const float*)d_in[3];
  const float* W_ih     = (const float*)d_in[4];
  const float* b_ih     = (const float*)d_in[5];
  const float* W_hh     = (const float*)d_in[6];
  const float* b_hh     = (const float*)d_in[7];
  const float* Wq       = (const float*)d_in[8];
  const float* bq       = (const float*)d_in[9];
  const float* Wk       = (const float*)d_in[10];
  const float* bk       = (const float*)d_in[11];
  const float* Wv       = (const float*)d_in[12];
  const float* bv       = (const float*)d_in[13];
  const float* W_aoa    = (const float*)d_in[14];
  const float* b_aoa    = (const float*)d_in[15];
  const float* pred_v   = (const float*)d_in[16];
  const float* pred_g   = (const float*)d_in[17];
  const float* pred_b   = (const float*)d_in[18];
  float* out = (float*)d_out;

  char* base = (char*)d_ws;
  size_t off = 0;
  auto alloc = [&](size_t bytes) -> char* {
    char* p = base + off;
    off = (off + bytes + 255) & ~(size_t)255;
    return p;
  };
  // persistent
  unsigned short* KV     = (unsigned short*)alloc((size_t)BB * NN * 2048 * 2);
  unsigned short* Wcat_b = (unsigned short*)alloc((size_t)4096 * 3072 * 2);
  unsigned short* Wn_b   = (unsigned short*)alloc((size_t)VV * DD * 2);
  unsigned short* Waoa_b = (unsigned short*)alloc((size_t)2048 * 2048 * 2);
  unsigned short* Wq_b   = (unsigned short*)alloc((size_t)DD * DD * 2);
  unsigned short* Wkv_b  = (unsigned short*)alloc((size_t)2048 * 1024 * 2);
  float* bkv             = (float*)alloc(2048 * 4);
  float* meanf           = (float*)alloc((size_t)BB * DD * 4);
  float* mbuf            = (float*)alloc((size_t)BB * DD * 4);
  // union region: encb (precompute only) aliases the step-phase buffers
  size_t encB  = (size_t)BB * NN * DD * 2;                 // 51.4 MB
  size_t stepB = 0;
  {
    size_t a = 0;
    auto c = [&](size_t b) { size_t p = a; a = (a + b + 255) & ~(size_t)255; return p; };
    c((size_t)4 * BB * 4096 * 4);   // gates
    c((size_t)8 * BB * DD * 4);     // qbuf
    c((size_t)8 * BB * 2048 * 4);   // abuf
    c((size_t)BB * 2048 * 2);       // xaoa
    c((size_t)BB * DD * 2);         // predin
    c((size_t)21 * BB * 3072 * 2);  // xcat
    stepB = a;
  }
  char* uni = alloc(encB > stepB ? encB : stepB);
  unsigned short* encb = (unsigned short*)uni;
  size_t ua = 0;
  auto carve = [&](size_t b) -> char* { char* p = uni + ua; ua = (ua + b + 255) & ~(size_t)255; return p; };
  float* gates           = (float*)carve((size_t)4 * BB * 4096 * 4);
  float* qbuf            = (float*)carve((size_t)8 * BB * DD * 4);
  float* abuf            = (float*)carve((size_t)8 * BB * 2048 * 4);
  unsigned short* xaoa   = (unsigned short*)carve((size_t)BB * 2048 * 2);
  unsigned short* predin = (unsigned short*)carve((size_t)BB * DD * 2);
  unsigned short* xcat   = (unsigned short*)carve((size_t)21 * BB * 3072 * 2);
  if (off > ws_size) return;   // ws too small: diagnostic no-op

  // ---- precompute ----
  meanconv_kernel<<<512, 256, 0, stream>>>(enc, meanf, encb);
  wcat4_kernel<<<12288, 256, 0, stream>>>(W_ih, W_hh, Wcat_b);
  conv4_kernel<<<1024, 256, 0, stream>>>(Wq, Wq_b);
  conv4_kernel<<<4096, 256, 0, stream>>>(W_aoa, Waoa_b);
  kvw4_kernel<<<2048, 256, 0, stream>>>(Wk, Wv, Wkv_b);
  bkv_kernel<<<8, 256, 0, stream>>>(bk, bv, bkv);
  wn_kernel<<<VV, 256, 0, stream>>>(pred_v, pred_g, Wn_b);
  gemm_kv<<<16 * 196, 256, 0, stream>>>(encb, Wkv_b, bkv, KV);
  // after gemm_kv, encb is dead -> step buffers (same region) may be written
  init_kernel<<<512, 256, 0, stream>>>(meanf, mbuf, xcat);
  emb4_kernel<<<2560, 256, 0, stream>>>(embed_W, captions, xcat);

  // ---- 20 recurrent steps ----
  for (int t = 0; t < TT; ++t) {
    unsigned short* xc = xcat + (size_t)t * BB * 3072;
    unsigned short* xn = xcat + (size_t)(t + 1) * BB * 3072;
    // gates: K=3072 (96 kt), nx=64, 4 splits x 24 kt
    gemm2<0><<<256, 256, 0, stream>>>(xc, 3072, Wcat_b, 3072, nullptr, gates, 4096, 64, 24, nullptr, 0);
    lstm_kernel<<<512, 256, 0, stream>>>(gates, b_ih, b_hh, mbuf, xaoa, xn);
    // q: K=1024 (32 kt), nx=16, 8 splits x 4 kt
    gemm2<0><<<128, 256, 0, stream>>>(xaoa + 1024, 2048, Wq_b, 1024, nullptr, qbuf, 1024, 16, 4, nullptr, 0);
    attn_kernel<<<BB * NHH, 256, 0, stream>>>(qbuf, bq, KV, xaoa);
    // aoa: K=2048 (64 kt), nx=32, 8 splits x 8 kt
    gemm2<0><<<256, 256, 0, stream>>>(xaoa, 2048, Waoa_b, 2048, nullptr, abuf, 2048, 32, 8, nullptr, 0);
    glu_kernel<<<512, 256, 0, stream>>>(abuf, b_aoa, meanf, predin, xn);
    // vocab: K=1024 (32 kt), nx=157, single split
    gemm2<2><<<157, 256, 0, stream>>>(predin, 1024, Wn_b, 1024, pred_b, out, VV, 157, 32, lengths, t);
  }
}

// Round 4
// 2043.711 us; speedup vs baseline: 2.7376x; 1.0241x over previous
//
#include <hip/hip_runtime.h>
#include <hip/hip_bf16.h>
#include <cstdint>

#define BB 128
#define TT 20
#define VV 10000
#define DD 1024
#define NHH 8
#define DHH 128
#define NN 196
#define DEPTH 3

typedef float f32x4 __attribute__((ext_vector_type(4)));
typedef __bf16 bf16x8 __attribute__((ext_vector_type(8)));
typedef unsigned int u32x4 __attribute__((ext_vector_type(4)));
typedef unsigned int u32x2 __attribute__((ext_vector_type(2)));

__device__ __forceinline__ unsigned short f2bf(float x) {
  unsigned u = __float_as_uint(x);
  u += 0x7FFFu + ((u >> 16) & 1u);
  return (unsigned short)(u >> 16);
}
__device__ __forceinline__ float bf2f(unsigned short h) {
  return __uint_as_float(((unsigned)h) << 16);
}
__device__ __forceinline__ float sigm(float x) { return 1.f / (1.f + __expf(-x)); }
__device__ __forceinline__ unsigned pk2(float lo, float hi) {
  return (unsigned)f2bf(lo) | ((unsigned)f2bf(hi) << 16);
}
// bijective chunked XCD swizzle (m204)
__device__ __forceinline__ int xcd_swz(int orig, int nb) {
  int q = nb >> 3, r = nb & 7;
  int x = orig & 7, i = orig >> 3;
  return (x < r ? x * (q + 1) : r * (q + 1) + (x - r) * q) + i;
}
__device__ __forceinline__ void gl16(const void* g, void* l) {
  __builtin_amdgcn_global_load_lds((const __attribute__((address_space(1))) void*)g,
                                   (__attribute__((address_space(3))) void*)l, 16, 0, 0);
}

#define WAITVM(n) asm volatile("s_waitcnt vmcnt(" #n ")" ::: "memory")
#define LGKM0()   asm volatile("s_waitcnt lgkmcnt(0)" ::: "memory")
#define SCHED0()  __builtin_amdgcn_sched_barrier(0)

// ---- unified deep-pipelined GEMM: C[M,N] = A[M,K] @ W[N,K]^T, BM=128, BK=64, DEPTH=3.
// LDS XOR-swizzle (T2): source pre-swizzled chunk^=(row&7); read side same involution.
// MODE 0: plain fp32 out (no bias, ldc=N)      [q projection]
// MODE 1: bf16 out + bias (ldc=N)              [KV projection]
// MODE 2: vocab fp32 out + bias + length mask  [predictions]
// MODE 3: gates + fused LSTM epilogue (W rows gate-interleaved r'=(d>>3)*32+g*8+(d&7))
// MODE 4: aoa + fused GLU epilogue   (W rows half-interleaved r'=(d>>4)*32+h*16+(d&15))
template<int BN, int MODE>
__launch_bounds__(256)
__global__ void gemmp(const unsigned short* __restrict__ A, int lda,
                      const unsigned short* __restrict__ W, int K, int N, int ncol,
                      const float* __restrict__ bias,
                      float* __restrict__ outF, unsigned short* __restrict__ outB,
                      float* __restrict__ mbuf, const float* __restrict__ meanf,
                      unsigned short* __restrict__ xaoa, unsigned short* __restrict__ xn,
                      const int* __restrict__ lengths, int tstep)
{
  constexpr int SZA = 128 * 128;          // bytes per A buffer (128 rows x 64 bf16)
  constexpr int SZB = BN * 128;
  constexpr int NJ = BN / 16;
  __shared__ char smem[DEPTH * (SZA + SZB)];

  const int wg = xcd_swz(blockIdx.x, gridDim.x);
  const int xi = wg % ncol, rowt = wg / ncol;
  const int colbase = xi * BN;
  const int rowbase = rowt * 128;
  const int tid = threadIdx.x;
  const int lane = tid & 63, wv = tid >> 6;
  const int wrow = wv * 32;
  const int lr = lane & 15;

  // staging geometry: per gl16 issue a wave covers 8 rows x 8 chunks (128B rows)
  const int srow = lane >> 3;                       // row within 8-group
  const int schunk = ((lane & 7) ^ srow) * 8;       // pre-swizzled 16B chunk (elements)
  const int nk = K >> 6;

  auto stage = [&](int t, int buf) {
    char* sA = smem + buf * (SZA + SZB);
    char* sB = sA + SZA;
    const int k0 = t << 6;
    #pragma unroll
    for (int s = 0; s < 4; ++s) {
      const int rb = s * 32 + wv * 8;
      gl16(A + (size_t)(rowbase + rb + srow) * lda + k0 + schunk, sA + rb * 128);
    }
    #pragma unroll
    for (int s = 0; s < BN / 32; ++s) {
      const int rb = s * 32 + wv * 8;
      int br = colbase + rb + srow;
      if (MODE == 2) br = br < N ? br : N - 1;
      gl16(W + (size_t)br * K + k0 + schunk, sB + rb * 128);
    }
  };

  f32x4 acc[2][NJ];
  const f32x4 zero = {0.f, 0.f, 0.f, 0.f};
  #pragma unroll
  for (int i = 0; i < 2; ++i)
    #pragma unroll
    for (int j = 0; j < NJ; ++j) acc[i][j] = zero;

  for (int t = 0; t < DEPTH; ++t) stage(t, t);

  const int axor = (lr & 7) << 4;
  const int ccol = (lane >> 4) * 16;
  int buf = 0;
  for (int i = 0; i < nk; ++i) {
    if (i < nk - 2)       { if (BN == 32) { WAITVM(10); } else { WAITVM(12); } }
    else if (i == nk - 2) { if (BN == 32) { WAITVM(5);  } else { WAITVM(6);  } }
    else                  { WAITVM(0); }
    __builtin_amdgcn_s_barrier();
    SCHED0();
    const char* sA = smem + buf * (SZA + SZB);
    const char* sB = sA + SZA;
    bf16x8 af[2][2], bfr[NJ][2];
    #pragma unroll
    for (int ii = 0; ii < 2; ++ii)
      #pragma unroll
      for (int kk = 0; kk < 2; ++kk)
        af[ii][kk] = *reinterpret_cast<const bf16x8*>(
            sA + (wrow + ii * 16 + lr) * 128 + ((kk * 64 + ccol) ^ axor));
    #pragma unroll
    for (int j = 0; j < NJ; ++j)
      #pragma unroll
      for (int kk = 0; kk < 2; ++kk)
        bfr[j][kk] = *reinterpret_cast<const bf16x8*>(
            sB + (j * 16 + lr) * 128 + ((kk * 64 + ccol) ^ axor));
    LGKM0();
    SCHED0();
    __builtin_amdgcn_s_barrier();   // all waves done reading this buffer
    SCHED0();
    if (i + DEPTH < nk) stage(i + DEPTH, buf);
    #pragma unroll
    for (int kk = 0; kk < 2; ++kk)
      #pragma unroll
      for (int ii = 0; ii < 2; ++ii)
        #pragma unroll
        for (int j = 0; j < NJ; ++j)
          acc[ii][j] = __builtin_amdgcn_mfma_f32_16x16x32_bf16(af[ii][kk], bfr[j][kk], acc[ii][j], 0, 0, 0);
    buf = (buf == DEPTH - 1) ? 0 : buf + 1;
  }

  const int rg4 = (lane >> 4) * 4;

  if constexpr (MODE == 0) {
    #pragma unroll
    for (int ii = 0; ii < 2; ++ii)
      #pragma unroll
      for (int j = 0; j < NJ; ++j) {
        const int gcol = colbase + j * 16 + lr;
        #pragma unroll
        for (int r = 0; r < 4; ++r)
          outF[(size_t)(wrow + ii * 16 + rg4 + r) * N + gcol] = acc[ii][j][r];
      }
  } else if constexpr (MODE == 1) {
    #pragma unroll
    for (int ii = 0; ii < 2; ++ii)
      #pragma unroll
      for (int j = 0; j < NJ; ++j) {
        const int gcol = colbase + j * 16 + lr;
        const float bv = bias[gcol];
        #pragma unroll
        for (int r = 0; r < 4; ++r)
          outB[(size_t)(rowbase + wrow + ii * 16 + rg4 + r) * N + gcol] = f2bf(acc[ii][j][r] + bv);
      }
  } else if constexpr (MODE == 2) {
    #pragma unroll
    for (int ii = 0; ii < 2; ++ii)
      #pragma unroll
      for (int j = 0; j < NJ; ++j) {
        const int gcol = colbase + j * 16 + lr;
        if (gcol >= N) continue;
        const float bv = bias[gcol];
        #pragma unroll
        for (int r = 0; r < 4; ++r) {
          const int gr = wrow + ii * 16 + rg4 + r;
          outF[((size_t)gr * TT + tstep) * VV + gcol] =
              (tstep < lengths[gr]) ? acc[ii][j][r] + bv : 0.f;
        }
      }
  } else if constexpr (MODE == 3) {
    // gates: thread owns gates {0,2} (lr<8) or {1,3} (lr>=8) for d=(colbase>>2)+(lr&7)
    float a0[2][4], a1[2][4];
    const float b0 = bias[colbase + lr], b1 = bias[colbase + 16 + lr];
    #pragma unroll
    for (int ii = 0; ii < 2; ++ii)
      #pragma unroll
      for (int r = 0; r < 4; ++r) {
        a0[ii][r] = acc[ii][0][r] + b0;
        a1[ii][r] = acc[ii][1][r] + b1;
      }
    const int d = (colbase >> 2) + (lr & 7);
    #pragma unroll
    for (int ii = 0; ii < 2; ++ii)
      #pragma unroll
      for (int r = 0; r < 4; ++r) {
        const float fg = __shfl_xor(a0[ii][r], 8);   // partner's gate 1 (f)
        const float og = __shfl_xor(a1[ii][r], 8);   // partner's gate 3 (o)
        if (lr < 8) {
          const int b = wrow + ii * 16 + rg4 + r;
          const float m2 = sigm(fg) * mbuf[(size_t)b * DD + d] + sigm(a0[ii][r]) * tanhf(a1[ii][r]);
          const float h2 = sigm(og) * tanhf(m2);
          mbuf[(size_t)b * DD + d] = m2;
          const unsigned short hb = f2bf(h2);
          xaoa[(size_t)b * 2048 + 1024 + d] = hb;
          xn[(size_t)b * 3072 + 2048 + d] = hb;
        }
      }
  } else {  // MODE 4: aoa + GLU
    const int d = (colbase >> 1) + lr;
    const float b0 = bias[colbase + lr], b1 = bias[colbase + 16 + lr];
    #pragma unroll
    for (int ii = 0; ii < 2; ++ii)
      #pragma unroll
      for (int r = 0; r < 4; ++r) {
        const int b = wrow + ii * 16 + rg4 + r;
        const float av1 = acc[ii][0][r] + b0;
        const float av2 = acc[ii][1][r] + b1;
        const float c2 = av1 * sigm(av2);
        outB[(size_t)b * DD + d] = f2bf(c2);                                   // predin
        xn[(size_t)b * 3072 + 1024 + d] = f2bf(meanf[(size_t)b * DD + d] + c2);
      }
  }
}

// ---- pointwise / prep kernels ----
__launch_bounds__(256)
__global__ void meanconv_kernel(const float* __restrict__ enc, float* __restrict__ meanf,
                                unsigned short* __restrict__ encb) {
  int b = blockIdx.x >> 2, d = (blockIdx.x & 3) * 256 + threadIdx.x;
  const float* p = enc + (size_t)b * NN * DD + d;
  unsigned short* q = encb + (size_t)b * NN * DD + d;
  float s = 0.f;
  for (int n = 0; n < NN; ++n) {
    float x = p[(size_t)n * DD];
    s += x;
    q[(size_t)n * DD] = f2bf(x);
  }
  meanf[(size_t)b * DD + d] = s * (1.0f / (float)NN);
}

__launch_bounds__(256)
__global__ void conv4_kernel(const float* __restrict__ src, unsigned short* __restrict__ dst) {
  int i = blockIdx.x * 256 + threadIdx.x;
  f32x4 v = *reinterpret_cast<const f32x4*>(src + (size_t)i * 4);
  u32x2 o = { pk2(v[0], v[1]), pk2(v[2], v[3]) };
  *reinterpret_cast<u32x2*>(dst + (size_t)i * 4) = o;
}

// gate-interleaved Wcat: new row r' <- orig row g*1024+d, r'=(d>>3)*32+g*8+(d&7)
__launch_bounds__(256)
__global__ void wcatI_kernel(const float* __restrict__ W_ih, const float* __restrict__ W_hh,
                             unsigned short* __restrict__ Wcat) {
  int i = blockIdx.x * 256 + threadIdx.x;     // 4096*768 vec4 chunks
  int rp = i / 768, c4 = (i - rp * 768) * 4;
  int rem = rp & 31, g = rem >> 3, d = (rp >> 5) * 8 + (rem & 7);
  int orig = g * 1024 + d;
  const float* src = (c4 < 2048) ? (W_ih + (size_t)orig * 2048 + c4)
                                 : (W_hh + (size_t)orig * 1024 + (c4 - 2048));
  f32x4 v = *reinterpret_cast<const f32x4*>(src);
  u32x2 o = { pk2(v[0], v[1]), pk2(v[2], v[3]) };
  *reinterpret_cast<u32x2*>(Wcat + (size_t)rp * 3072 + c4) = o;
}

// half-interleaved W_aoa: r'=(d>>4)*32+half*16+(d&15) <- orig half*1024+d
__launch_bounds__(256)
__global__ void waoaI_kernel(const float* __restrict__ W_aoa, unsigned short* __restrict__ Wo) {
  int i = blockIdx.x * 256 + threadIdx.x;     // 2048*512 vec4 chunks
  int rp = i >> 9, c4 = (i & 511) * 4;
  int rem = rp & 31, half = rem >> 4, d = (rp >> 5) * 16 + (rem & 15);
  int orig = half * 1024 + d;
  f32x4 v = *reinterpret_cast<const f32x4*>(W_aoa + (size_t)orig * 2048 + c4);
  u32x2 o = { pk2(v[0], v[1]), pk2(v[2], v[3]) };
  *reinterpret_cast<u32x2*>(Wo + (size_t)rp * 2048 + c4) = o;
}

__launch_bounds__(256)
__global__ void kvw4_kernel(const float* __restrict__ Wk, const float* __restrict__ Wv,
                            unsigned short* __restrict__ Wkv) {
  int i = blockIdx.x * 256 + threadIdx.x;
  int row = i >> 8, c4 = (i & 255) << 2;
  const float* src = (row < 1024) ? (Wk + (size_t)row * 1024 + c4)
                                  : (Wv + (size_t)(row - 1024) * 1024 + c4);
  f32x4 v = *reinterpret_cast<const f32x4*>(src);
  u32x2 o = { pk2(v[0], v[1]), pk2(v[2], v[3]) };
  *reinterpret_cast<u32x2*>(Wkv + (size_t)row * 1024 + c4) = o;
}

__launch_bounds__(256)
__global__ void bias_kernel(const float* __restrict__ b_ih, const float* __restrict__ b_hh,
                            const float* __restrict__ b_aoa, const float* __restrict__ bk,
                            const float* __restrict__ bv, float* __restrict__ bcombI,
                            float* __restrict__ baoaI, float* __restrict__ bkv) {
  int i = blockIdx.x * 256 + threadIdx.x;   // 4096 total
  {
    int rem = i & 31, g = rem >> 3, d = (i >> 5) * 8 + (rem & 7);
    int orig = g * 1024 + d;
    bcombI[i] = b_ih[orig] + b_hh[orig];
  }
  if (i < 2048) {
    int rem = i & 31, half = rem >> 4, d = (i >> 5) * 16 + (rem & 15);
    baoaI[i] = b_aoa[half * 1024 + d];
    bkv[i] = (i < 1024) ? bk[i] : bv[i - 1024];
  }
}

__launch_bounds__(256)
__global__ void init_kernel(const float* __restrict__ meanf, float* __restrict__ m,
                            unsigned short* __restrict__ xcat0) {
  int idx = blockIdx.x * 256 + threadIdx.x;
  int b = idx >> 10, d = idx & 1023;
  m[idx] = 0.f;
  xcat0[(size_t)b * 3072 + 1024 + d] = f2bf(meanf[idx]);
  xcat0[(size_t)b * 3072 + 2048 + d] = 0;
}

__launch_bounds__(256)
__global__ void wn_kernel(const float* __restrict__ pred_v, const float* __restrict__ pred_g,
                          unsigned short* __restrict__ Wn) {
  int v = blockIdx.x, tid = threadIdx.x;
  const float* row = pred_v + (size_t)v * DD;
  float s = 0.f;
  for (int j = tid; j < DD; j += 256) { float x = row[j]; s += x * x; }
  #pragma unroll
  for (int o = 32; o; o >>= 1) s += __shfl_down(s, o);
  __shared__ float red[4];
  if ((tid & 63) == 0) red[tid >> 6] = s;
  __syncthreads();
  float inv = pred_g[v] * rsqrtf(red[0] + red[1] + red[2] + red[3]);
  for (int j = tid; j < DD; j += 256) Wn[(size_t)v * DD + j] = f2bf(row[j] * inv);
}

__launch_bounds__(256)
__global__ void emb4_kernel(const float* __restrict__ embed_W, const int* __restrict__ captions,
                            unsigned short* __restrict__ xcat) {
  int i = blockIdx.x * 256 + threadIdx.x;
  int j4 = (i & 255) << 2, b = (i >> 8) & 127, t = i >> 15;
  int tok = captions[b * TT + t];
  f32x4 v = *reinterpret_cast<const f32x4*>(embed_W + (size_t)tok * DD + j4);
  u32x2 o = { pk2(v[0], v[1]), pk2(v[2], v[3]) };
  *reinterpret_cast<u32x2*>(xcat + ((size_t)t * BB + b) * 3072 + j4) = o;
}

__launch_bounds__(256)
__global__ void attn_kernel(const float* __restrict__ qbuf, const float* __restrict__ bq,
                            const unsigned short* __restrict__ KV, unsigned short* __restrict__ xaoa) {
  const int bh = blockIdx.x, b = bh >> 3, h = bh & 7;
  const int tid = threadIdx.x;
  __shared__ float qs[DHH];
  __shared__ float sc[NN];
  __shared__ float pvred[2][DHH];
  if (tid < DHH) qs[tid] = bq[h * DHH + tid] + qbuf[(size_t)b * DD + h * DHH + tid];
  __syncthreads();
  if (tid < NN) {
    const unsigned short* kr = KV + ((size_t)(b * NN + tid)) * 2048 + h * DHH;
    float a = 0.f;
    #pragma unroll
    for (int j = 0; j < 16; ++j) {
      u32x4 kk = *reinterpret_cast<const u32x4*>(kr + j * 8);
      #pragma unroll
      for (int w = 0; w < 4; ++w) {
        a += bf2f((unsigned short)(kk[w] & 0xffffu)) * qs[j * 8 + w * 2]
           + bf2f((unsigned short)(kk[w] >> 16)) * qs[j * 8 + w * 2 + 1];
      }
    }
    sc[tid] = a * 0.08838834764831845f;
  }
  __syncthreads();
  float mx = -1e30f;
  for (int n = 0; n < NN; ++n) mx = fmaxf(mx, sc[n]);
  __syncthreads();
  if (tid < NN) sc[tid] = __expf(sc[tid] - mx);
  __syncthreads();
  float sm = 0.f;
  for (int n = 0; n < NN; ++n) sm += sc[n];
  const float inv = 1.f / sm;
  const int d = tid & 127, half = tid >> 7;
  const unsigned short* vr = KV + ((size_t)(b * NN + half * 98)) * 2048 + 1024 + h * DHH + d;
  float a = 0.f;
  for (int n = 0; n < 98; ++n) a += sc[half * 98 + n] * bf2f(vr[(size_t)n * 2048]);
  pvred[half][d] = a;
  __syncthreads();
  if (tid < DHH)
    xaoa[(size_t)b * 2048 + h * DHH + tid] = f2bf((pvred[0][tid] + pvred[1][tid]) * inv);
}

extern "C" void kernel_launch(void* const* d_in, const int* in_sizes, int n_in,
                              void* d_out, int out_size, void* d_ws, size_t ws_size,
                              hipStream_t stream) {
  const float* enc      = (const float*)d_in[0];
  const int*   captions = (const int*)d_in[1];
  const int*   lengths  = (const int*)d_in[2];
  const float* embed_W  = (const float*)d_in[3];
  const float* W_ih     = (const float*)d_in[4];
  const float* b_ih     = (const float*)d_in[5];
  const float* W_hh     = (const float*)d_in[6];
  const float* b_hh     = (const float*)d_in[7];
  const float* Wq       = (const float*)d_in[8];
  const float* bq       = (const float*)d_in[9];
  const float* Wk       = (const float*)d_in[10];
  const float* bk       = (const float*)d_in[11];
  const float* Wv       = (const float*)d_in[12];
  const float* bv       = (const float*)d_in[13];
  const float* W_aoa    = (const float*)d_in[14];
  const float* b_aoa    = (const float*)d_in[15];
  const float* pred_v   = (const float*)d_in[16];
  const float* pred_g   = (const float*)d_in[17];
  const float* pred_b   = (const float*)d_in[18];
  float* out = (float*)d_out;

  char* base = (char*)d_ws;
  size_t off = 0;
  auto alloc = [&](size_t bytes) -> char* {
    char* p = base + off;
    off = (off + bytes + 255) & ~(size_t)255;
    return p;
  };
  // persistent
  unsigned short* KV     = (unsigned short*)alloc((size_t)BB * NN * 2048 * 2);
  unsigned short* WcatI  = (unsigned short*)alloc((size_t)4096 * 3072 * 2);
  unsigned short* Wn_b   = (unsigned short*)alloc((size_t)VV * DD * 2);
  unsigned short* WaoaI  = (unsigned short*)alloc((size_t)2048 * 2048 * 2);
  unsigned short* Wq_b   = (unsigned short*)alloc((size_t)DD * DD * 2);
  unsigned short* Wkv_b  = (unsigned short*)alloc((size_t)2048 * 1024 * 2);
  float* bcombI          = (float*)alloc(4096 * 4);
  float* baoaI           = (float*)alloc(2048 * 4);
  float* bkv             = (float*)alloc(2048 * 4);
  float* meanf           = (float*)alloc((size_t)BB * DD * 4);
  float* mbuf            = (float*)alloc((size_t)BB * DD * 4);
  // union: encb (precompute) aliases step buffers
  size_t encB = (size_t)BB * NN * DD * 2;
  char* uni = alloc(encB);
  unsigned short* encb = (unsigned short*)uni;
  size_t ua = 0;
  auto carve = [&](size_t b) -> char* { char* p = uni + ua; ua = (ua + b + 255) & ~(size_t)255; return p; };
  float* qbuf            = (float*)carve((size_t)BB * DD * 4);
  unsigned short* xaoa   = (unsigned short*)carve((size_t)BB * 2048 * 2);
  unsigned short* predin = (unsigned short*)carve((size_t)BB * DD * 2);
  unsigned short* xcat   = (unsigned short*)carve((size_t)21 * BB * 3072 * 2);
  if (off > ws_size || ua > encB) return;

  // ---- precompute ----
  meanconv_kernel<<<512, 256, 0, stream>>>(enc, meanf, encb);
  wcatI_kernel<<<12288, 256, 0, stream>>>(W_ih, W_hh, WcatI);
  conv4_kernel<<<1024, 256, 0, stream>>>(Wq, Wq_b);
  waoaI_kernel<<<4096, 256, 0, stream>>>(W_aoa, WaoaI);
  kvw4_kernel<<<2048, 256, 0, stream>>>(Wk, Wv, Wkv_b);
  bias_kernel<<<16, 256, 0, stream>>>(b_ih, b_hh, b_aoa, bk, bv, bcombI, baoaI, bkv);
  wn_kernel<<<VV, 256, 0, stream>>>(pred_v, pred_g, Wn_b);
  // KV projection: grid 196 row-tiles x 32 col-tiles
  gemmp<64, 1><<<6272, 256, 0, stream>>>(encb, 1024, Wkv_b, 1024, 2048, 32, bkv,
                                         nullptr, KV, nullptr, nullptr, nullptr, nullptr, nullptr, 0);
  // encb dead -> step buffers usable
  init_kernel<<<512, 256, 0, stream>>>(meanf, mbuf, xcat);
  emb4_kernel<<<2560, 256, 0, stream>>>(embed_W, captions, xcat);

  // ---- 20 recurrent steps ----
  for (int t = 0; t < TT; ++t) {
    unsigned short* xc = xcat + (size_t)t * BB * 3072;
    unsigned short* xn = xcat + (size_t)(t + 1) * BB * 3072;
    // gates + LSTM fused: N=4096 interleaved, grid 128
    gemmp<32, 3><<<128, 256, 0, stream>>>(xc, 3072, WcatI, 3072, 4096, 128, bcombI,
                                          nullptr, nullptr, mbuf, nullptr, xaoa, xn, nullptr, 0);
    // q projection: grid 32
    gemmp<32, 0><<<32, 256, 0, stream>>>(xaoa + 1024, 2048, Wq_b, 1024, 1024, 32, nullptr,
                                         qbuf, nullptr, nullptr, nullptr, nullptr, nullptr, nullptr, 0);
    attn_kernel<<<BB * NHH, 256, 0, stream>>>(qbuf, bq, KV, xaoa);
    // aoa + GLU fused: N=2048 interleaved, grid 64
    gemmp<32, 4><<<64, 256, 0, stream>>>(xaoa, 2048, WaoaI, 2048, 2048, 64, baoaI,
                                         nullptr, predin, nullptr, meanf, nullptr, xn, nullptr, 0);
    // vocab: grid 313
    gemmp<32, 2><<<313, 256, 0, stream>>>(predin, 1024, Wn_b, 1024, VV, 313, pred_b,
                                          out, nullptr, nullptr, nullptr, nullptr, nullptr, lengths, t);
  }
}

// Round 5
// 1784.801 us; speedup vs baseline: 3.1348x; 1.1451x over previous
//
#include <hip/hip_runtime.h>
#include <hip/hip_bf16.h>
#include <cstdint>

#define BB 128
#define TT 20
#define VV 10000
#define DD 1024
#define NHH 8
#define DHH 128
#define NN 196

typedef float f32x4 __attribute__((ext_vector_type(4)));
typedef __bf16 bf16x8 __attribute__((ext_vector_type(8)));
typedef unsigned int u32x4 __attribute__((ext_vector_type(4)));
typedef unsigned int u32x2 __attribute__((ext_vector_type(2)));

__device__ __forceinline__ unsigned short f2bf(float x) {
  unsigned u = __float_as_uint(x);
  u += 0x7FFFu + ((u >> 16) & 1u);
  return (unsigned short)(u >> 16);
}
__device__ __forceinline__ float bf2f(unsigned short h) {
  return __uint_as_float(((unsigned)h) << 16);
}
__device__ __forceinline__ float sigm(float x) { return 1.f / (1.f + __expf(-x)); }
__device__ __forceinline__ unsigned pk2(float lo, float hi) {
  return (unsigned)f2bf(lo) | ((unsigned)f2bf(hi) << 16);
}
// bijective chunked XCD swizzle (m204)
__device__ __forceinline__ int xcd_swz(int orig, int nb) {
  int q = nb >> 3, r = nb & 7;
  int x = orig & 7, i = orig >> 3;
  return (x < r ? x * (q + 1) : r * (q + 1) + (x - r) * q) + i;
}
__device__ __forceinline__ void gl16(const void* g, void* l) {
  __builtin_amdgcn_global_load_lds((const __attribute__((address_space(1))) void*)g,
                                   (__attribute__((address_space(3))) void*)l, 16, 0, 0);
}

template<int N> __device__ __forceinline__ void waitvm() {
  if constexpr (N == 0)       asm volatile("s_waitcnt vmcnt(0)" ::: "memory");
  else if constexpr (N == 5)  asm volatile("s_waitcnt vmcnt(5)" ::: "memory");
  else if constexpr (N == 8)  asm volatile("s_waitcnt vmcnt(8)" ::: "memory");
  else if constexpr (N == 10) asm volatile("s_waitcnt vmcnt(10)" ::: "memory");
  else if constexpr (N == 12) asm volatile("s_waitcnt vmcnt(12)" ::: "memory");
}
#define LGKM0()  asm volatile("s_waitcnt lgkmcnt(0)" ::: "memory")
#define SCHED0() __builtin_amdgcn_sched_barrier(0)

// ---- unified deep-pipelined GEMM: C[M,N] = A[M,K-slice] @ W[N,:]^T, BM=128, BK=64.
// LDS XOR-swizzle (T2) via pre-swizzled global source; counted vmcnt (T3/T4).
// MODE 0: fp32 out, multi-rowtile (ldc=N)                      [Eall precompute]
// MODE 1: bf16 out + bias, multi-rowtile                        [KV projection]
// MODE 2: vocab batched: rows=(t*128+b), bias+mask -> out[B,T,V]
// MODE 3: gates + Eall add + fused LSTM epilogue (W gate-interleaved)
// MODE 4: aoa + fused GLU epilogue (W half-interleaved)
// MODE 5: fp32 out, split-K (rowt = split index, M=128)         [q projection]
template<int BN, int MODE, int DEP>
__launch_bounds__(256)
__global__ void gemmp(const unsigned short* __restrict__ A, int lda,
                      const unsigned short* __restrict__ W, int ldw,
                      int nkt, int N, int ncol,
                      const float* __restrict__ bias,
                      float* __restrict__ outF, unsigned short* __restrict__ outB,
                      float* __restrict__ mbuf, const float* __restrict__ meanf,
                      unsigned short* __restrict__ xaoa, unsigned short* __restrict__ xn2,
                      const int* __restrict__ lengths)
{
  constexpr int SZA = 128 * 128;
  constexpr int SZB = BN * 128;
  constexpr int NJ = BN / 16;
  constexpr int S = 4 + BN / 32;            // gl16 issues per thread per stage
  __shared__ char smem[DEP * (SZA + SZB)];

  const int wg = xcd_swz(blockIdx.x, gridDim.x);
  const int xi = wg % ncol, rowt = wg / ncol;
  const int colbase = xi * BN;
  const int rowbase = (MODE == 5) ? 0 : rowt * 128;
  const int k0base = (MODE == 5) ? rowt * nkt * 64 : 0;
  const int tid = threadIdx.x;
  const int lane = tid & 63, wv = tid >> 6;
  const int wrow = wv * 32;
  const int lr = lane & 15;

  const int srow = lane >> 3;
  const int schunk = ((lane & 7) ^ srow) * 8;   // pre-swizzled 16B chunk

  auto stage = [&](int t, int buf) {
    char* sA = smem + buf * (SZA + SZB);
    char* sB = sA + SZA;
    const int k0 = k0base + (t << 6);
    #pragma unroll
    for (int s = 0; s < 4; ++s) {
      const int rb = s * 32 + wv * 8;
      gl16(A + (size_t)(rowbase + rb + srow) * lda + k0 + schunk, sA + rb * 128);
    }
    #pragma unroll
    for (int s = 0; s < BN / 32; ++s) {
      const int rb = s * 32 + wv * 8;
      int br = colbase + rb + srow;
      if (MODE == 2) br = br < N ? br : N - 1;
      gl16(W + (size_t)br * ldw + k0 + schunk, sB + rb * 128);
    }
  };

  f32x4 acc[2][NJ];
  const f32x4 zero = {0.f, 0.f, 0.f, 0.f};
  #pragma unroll
  for (int i = 0; i < 2; ++i)
    #pragma unroll
    for (int j = 0; j < NJ; ++j) acc[i][j] = zero;

  #pragma unroll
  for (int t = 0; t < DEP; ++t) stage(t, t);

  const int axor = (lr & 7) << 4;
  const int ccol = (lane >> 4) * 16;
  int buf = 0;
  for (int i = 0; i < nkt; ++i) {
    const int rem = nkt - 1 - i;
    if (rem >= DEP - 1)            waitvm<S * (DEP - 1)>();
    else if (DEP > 2 && rem == 1)  waitvm<S>();
    else                           waitvm<0>();
    __builtin_amdgcn_s_barrier();
    SCHED0();
    const char* sA = smem + buf * (SZA + SZB);
    const char* sB = sA + SZA;
    bf16x8 af[2][2], bfr[NJ][2];
    #pragma unroll
    for (int ii = 0; ii < 2; ++ii)
      #pragma unroll
      for (int kk = 0; kk < 2; ++kk)
        af[ii][kk] = *reinterpret_cast<const bf16x8*>(
            sA + (wrow + ii * 16 + lr) * 128 + ((kk * 64 + ccol) ^ axor));
    #pragma unroll
    for (int j = 0; j < NJ; ++j)
      #pragma unroll
      for (int kk = 0; kk < 2; ++kk)
        bfr[j][kk] = *reinterpret_cast<const bf16x8*>(
            sB + (j * 16 + lr) * 128 + ((kk * 64 + ccol) ^ axor));
    LGKM0();
    SCHED0();
    __builtin_amdgcn_s_barrier();
    SCHED0();
    if (i + DEP < nkt) stage(i + DEP, buf);
    #pragma unroll
    for (int kk = 0; kk < 2; ++kk)
      #pragma unroll
      for (int ii = 0; ii < 2; ++ii)
        #pragma unroll
        for (int j = 0; j < NJ; ++j)
          acc[ii][j] = __builtin_amdgcn_mfma_f32_16x16x32_bf16(af[ii][kk], bfr[j][kk], acc[ii][j], 0, 0, 0);
    buf = (buf == DEP - 1) ? 0 : buf + 1;
  }

  const int rg4 = (lane >> 4) * 4;

  if constexpr (MODE == 0) {
    #pragma unroll
    for (int ii = 0; ii < 2; ++ii)
      #pragma unroll
      for (int j = 0; j < NJ; ++j) {
        const int gcol = colbase + j * 16 + lr;
        #pragma unroll
        for (int r = 0; r < 4; ++r)
          outF[(size_t)(rowbase + wrow + ii * 16 + rg4 + r) * N + gcol] = acc[ii][j][r];
      }
  } else if constexpr (MODE == 5) {
    float* dst = outF + (size_t)rowt * 128 * N;
    #pragma unroll
    for (int ii = 0; ii < 2; ++ii)
      #pragma unroll
      for (int j = 0; j < NJ; ++j) {
        const int gcol = colbase + j * 16 + lr;
        #pragma unroll
        for (int r = 0; r < 4; ++r)
          dst[(size_t)(wrow + ii * 16 + rg4 + r) * N + gcol] = acc[ii][j][r];
      }
  } else if constexpr (MODE == 1) {
    #pragma unroll
    for (int ii = 0; ii < 2; ++ii)
      #pragma unroll
      for (int j = 0; j < NJ; ++j) {
        const int gcol = colbase + j * 16 + lr;
        const float bv = bias[gcol];
        #pragma unroll
        for (int r = 0; r < 4; ++r)
          outB[(size_t)(rowbase + wrow + ii * 16 + rg4 + r) * N + gcol] = f2bf(acc[ii][j][r] + bv);
      }
  } else if constexpr (MODE == 2) {
    #pragma unroll
    for (int ii = 0; ii < 2; ++ii)
      #pragma unroll
      for (int j = 0; j < NJ; ++j) {
        const int gcol = colbase + j * 16 + lr;
        if (gcol >= N) continue;
        const float bv = bias[gcol];
        #pragma unroll
        for (int r = 0; r < 4; ++r) {
          const int gr = rowbase + wrow + ii * 16 + rg4 + r;   // t*128 + b
          const int tt = gr >> 7, bb = gr & 127;
          outF[((size_t)bb * TT + tt) * VV + gcol] =
              (tt < lengths[bb]) ? acc[ii][j][r] + bv : 0.f;
        }
      }
  } else if constexpr (MODE == 3) {
    // outF = Eall slice [128][4096]; gates interleaved: 32-col group = 8 d x 4 gates
    const float b0 = bias[colbase + lr], b1 = bias[colbase + 16 + lr];
    float a0[2][4], a1[2][4];
    #pragma unroll
    for (int ii = 0; ii < 2; ++ii)
      #pragma unroll
      for (int r = 0; r < 4; ++r) {
        const int b = wrow + ii * 16 + rg4 + r;
        a0[ii][r] = acc[ii][0][r] + b0 + outF[(size_t)b * 4096 + colbase + lr];
        a1[ii][r] = acc[ii][1][r] + b1 + outF[(size_t)b * 4096 + colbase + 16 + lr];
      }
    const int d = (colbase >> 2) + (lr & 7);
    #pragma unroll
    for (int ii = 0; ii < 2; ++ii)
      #pragma unroll
      for (int r = 0; r < 4; ++r) {
        const float fg = __shfl_xor(a0[ii][r], 8);   // partner gate f
        const float og = __shfl_xor(a1[ii][r], 8);   // partner gate o
        if (lr < 8) {
          const int b = wrow + ii * 16 + rg4 + r;
          const float m2 = sigm(fg) * mbuf[(size_t)b * DD + d] + sigm(a0[ii][r]) * tanhf(a1[ii][r]);
          const float h2 = sigm(og) * tanhf(m2);
          mbuf[(size_t)b * DD + d] = m2;
          const unsigned short hb = f2bf(h2);
          xaoa[(size_t)b * 2048 + 1024 + d] = hb;
          xn2[(size_t)b * 2048 + 1024 + d] = hb;
        }
      }
  } else {  // MODE 4: aoa + GLU
    const int d = (colbase >> 1) + lr;
    const float b0 = bias[colbase + lr], b1 = bias[colbase + 16 + lr];
    #pragma unroll
    for (int ii = 0; ii < 2; ++ii)
      #pragma unroll
      for (int r = 0; r < 4; ++r) {
        const int b = wrow + ii * 16 + rg4 + r;
        const float av1 = acc[ii][0][r] + b0;
        const float av2 = acc[ii][1][r] + b1;
        const float c2 = av1 * sigm(av2);
        outB[(size_t)b * DD + d] = f2bf(c2);                                  // predin[t]
        xn2[(size_t)b * 2048 + d] = f2bf(meanf[(size_t)b * DD + d] + c2);     // ctx+mean
      }
  }
}

// ---- pointwise / prep kernels ----
__launch_bounds__(256)
__global__ void meanconv_kernel(const float* __restrict__ enc, float* __restrict__ meanf,
                                unsigned short* __restrict__ encb) {
  int b = blockIdx.x >> 2, d = (blockIdx.x & 3) * 256 + threadIdx.x;
  const float* p = enc + (size_t)b * NN * DD + d;
  unsigned short* q = encb + (size_t)b * NN * DD + d;
  float s = 0.f;
  for (int n = 0; n < NN; ++n) {
    float x = p[(size_t)n * DD];
    s += x;
    q[(size_t)n * DD] = f2bf(x);
  }
  meanf[(size_t)b * DD + d] = s * (1.0f / (float)NN);
}

__launch_bounds__(256)
__global__ void conv4_kernel(const float* __restrict__ src, unsigned short* __restrict__ dst) {
  int i = blockIdx.x * 256 + threadIdx.x;
  f32x4 v = *reinterpret_cast<const f32x4*>(src + (size_t)i * 4);
  u32x2 o = { pk2(v[0], v[1]), pk2(v[2], v[3]) };
  *reinterpret_cast<u32x2*>(dst + (size_t)i * 4) = o;
}

// gate-interleaved Wcat: r'=(d>>3)*32+g*8+(d&7) <- orig g*1024+d; cols [emb|mean+ctx|h]
__launch_bounds__(256)
__global__ void wcatI_kernel(const float* __restrict__ W_ih, const float* __restrict__ W_hh,
                             unsigned short* __restrict__ Wcat) {
  int i = blockIdx.x * 256 + threadIdx.x;
  int rp = i / 768, c4 = (i - rp * 768) * 4;
  int rem = rp & 31, g = rem >> 3, d = (rp >> 5) * 8 + (rem & 7);
  int orig = g * 1024 + d;
  const float* src = (c4 < 2048) ? (W_ih + (size_t)orig * 2048 + c4)
                                 : (W_hh + (size_t)orig * 1024 + (c4 - 2048));
  f32x4 v = *reinterpret_cast<const f32x4*>(src);
  u32x2 o = { pk2(v[0], v[1]), pk2(v[2], v[3]) };
  *reinterpret_cast<u32x2*>(Wcat + (size_t)rp * 3072 + c4) = o;
}

// half-interleaved W_aoa: r'=(d>>4)*32+half*16+(d&15)
__launch_bounds__(256)
__global__ void waoaI_kernel(const float* __restrict__ W_aoa, unsigned short* __restrict__ Wo) {
  int i = blockIdx.x * 256 + threadIdx.x;
  int rp = i >> 9, c4 = (i & 511) * 4;
  int rem = rp & 31, half = rem >> 4, d = (rp >> 5) * 16 + (rem & 15);
  int orig = half * 1024 + d;
  f32x4 v = *reinterpret_cast<const f32x4*>(W_aoa + (size_t)orig * 2048 + c4);
  u32x2 o = { pk2(v[0], v[1]), pk2(v[2], v[3]) };
  *reinterpret_cast<u32x2*>(Wo + (size_t)rp * 2048 + c4) = o;
}

__launch_bounds__(256)
__global__ void kvw4_kernel(const float* __restrict__ Wk, const float* __restrict__ Wv,
                            unsigned short* __restrict__ Wkv) {
  int i = blockIdx.x * 256 + threadIdx.x;
  int row = i >> 8, c4 = (i & 255) << 2;
  const float* src = (row < 1024) ? (Wk + (size_t)row * 1024 + c4)
                                  : (Wv + (size_t)(row - 1024) * 1024 + c4);
  f32x4 v = *reinterpret_cast<const f32x4*>(src);
  u32x2 o = { pk2(v[0], v[1]), pk2(v[2], v[3]) };
  *reinterpret_cast<u32x2*>(Wkv + (size_t)row * 1024 + c4) = o;
}

__launch_bounds__(256)
__global__ void bias_kernel(const float* __restrict__ b_ih, const float* __restrict__ b_hh,
                            const float* __restrict__ b_aoa, const float* __restrict__ bk,
                            const float* __restrict__ bv, float* __restrict__ bcombI,
                            float* __restrict__ baoaI, float* __restrict__ bkv) {
  int i = blockIdx.x * 256 + threadIdx.x;
  {
    int rem = i & 31, g = rem >> 3, d = (i >> 5) * 8 + (rem & 7);
    int orig = g * 1024 + d;
    bcombI[i] = b_ih[orig] + b_hh[orig];
  }
  if (i < 2048) {
    int rem = i & 31, half = rem >> 4, d = (i >> 5) * 16 + (rem & 15);
    baoaI[i] = b_aoa[half * 1024 + d];
    bkv[i] = (i < 1024) ? bk[i] : bv[i - 1024];
  }
}

__launch_bounds__(256)
__global__ void init_kernel(const float* __restrict__ meanf, float* __restrict__ m,
                            unsigned short* __restrict__ x2_0) {
  int idx = blockIdx.x * 256 + threadIdx.x;
  int b = idx >> 10, d = idx & 1023;
  m[idx] = 0.f;
  x2_0[(size_t)b * 2048 + d] = f2bf(meanf[idx]);
  x2_0[(size_t)b * 2048 + 1024 + d] = 0;
}

__launch_bounds__(256)
__global__ void wn_kernel(const float* __restrict__ pred_v, const float* __restrict__ pred_g,
                          unsigned short* __restrict__ Wn) {
  int v = blockIdx.x, tid = threadIdx.x;
  const float* row = pred_v + (size_t)v * DD;
  float s = 0.f;
  for (int j = tid; j < DD; j += 256) { float x = row[j]; s += x * x; }
  #pragma unroll
  for (int o = 32; o; o >>= 1) s += __shfl_down(s, o);
  __shared__ float red[4];
  if ((tid & 63) == 0) red[tid >> 6] = s;
  __syncthreads();
  float inv = pred_g[v] * rsqrtf(red[0] + red[1] + red[2] + red[3]);
  for (int j = tid; j < DD; j += 256) Wn[(size_t)v * DD + j] = f2bf(row[j] * inv);
}

__launch_bounds__(256)
__global__ void emb4_kernel(const float* __restrict__ embed_W, const int* __restrict__ captions,
                            unsigned short* __restrict__ embAll) {
  int i = blockIdx.x * 256 + threadIdx.x;     // 20*128*256 vec4 chunks
  int j4 = (i & 255) << 2, b = (i >> 8) & 127, t = i >> 15;
  int tok = captions[b * TT + t];
  f32x4 v = *reinterpret_cast<const f32x4*>(embed_W + (size_t)tok * DD + j4);
  u32x2 o = { pk2(v[0], v[1]), pk2(v[2], v[3]) };
  *reinterpret_cast<u32x2*>(embAll + ((size_t)t * BB + b) * DD + j4) = o;
}

__launch_bounds__(256)
__global__ void attn_kernel(const float* __restrict__ qbuf, const float* __restrict__ bq,
                            const unsigned short* __restrict__ KV, unsigned short* __restrict__ xaoa) {
  const int bh = blockIdx.x, b = bh >> 3, h = bh & 7;
  const int tid = threadIdx.x;
  __shared__ float qs[DHH];
  __shared__ float sc[NN];
  __shared__ float pvred[2][DHH];
  if (tid < DHH)
    qs[tid] = bq[h * DHH + tid] + qbuf[(size_t)b * DD + h * DHH + tid]
            + qbuf[(size_t)BB * DD + (size_t)b * DD + h * DHH + tid];
  __syncthreads();
  if (tid < NN) {
    const unsigned short* kr = KV + ((size_t)(b * NN + tid)) * 2048 + h * DHH;
    float a = 0.f;
    #pragma unroll
    for (int j = 0; j < 16; ++j) {
      u32x4 kk = *reinterpret_cast<const u32x4*>(kr + j * 8);
      #pragma unroll
      for (int w = 0; w < 4; ++w) {
        a += bf2f((unsigned short)(kk[w] & 0xffffu)) * qs[j * 8 + w * 2]
           + bf2f((unsigned short)(kk[w] >> 16)) * qs[j * 8 + w * 2 + 1];
      }
    }
    sc[tid] = a * 0.08838834764831845f;
  }
  __syncthreads();
  float mx = -1e30f;
  for (int n = 0; n < NN; ++n) mx = fmaxf(mx, sc[n]);
  __syncthreads();
  if (tid < NN) sc[tid] = __expf(sc[tid] - mx);
  __syncthreads();
  float sm = 0.f;
  for (int n = 0; n < NN; ++n) sm += sc[n];
  const float inv = 1.f / sm;
  const int d = tid & 127, half = tid >> 7;
  const unsigned short* vr = KV + ((size_t)(b * NN + half * 98)) * 2048 + 1024 + h * DHH + d;
  float a = 0.f;
  for (int n = 0; n < 98; ++n) a += sc[half * 98 + n] * bf2f(vr[(size_t)n * 2048]);
  pvred[half][d] = a;
  __syncthreads();
  if (tid < DHH)
    xaoa[(size_t)b * 2048 + h * DHH + tid] = f2bf((pvred[0][tid] + pvred[1][tid]) * inv);
}

extern "C" void kernel_launch(void* const* d_in, const int* in_sizes, int n_in,
                              void* d_out, int out_size, void* d_ws, size_t ws_size,
                              hipStream_t stream) {
  const float* enc      = (const float*)d_in[0];
  const int*   captions = (const int*)d_in[1];
  const int*   lengths  = (const int*)d_in[2];
  const float* embed_W  = (const float*)d_in[3];
  const float* W_ih     = (const float*)d_in[4];
  const float* b_ih     = (const float*)d_in[5];
  const float* W_hh     = (const float*)d_in[6];
  const float* b_hh     = (const float*)d_in[7];
  const float* Wq       = (const float*)d_in[8];
  const float* bq       = (const float*)d_in[9];
  const float* Wk       = (const float*)d_in[10];
  const float* bk       = (const float*)d_in[11];
  const float* Wv       = (const float*)d_in[12];
  const float* bv       = (const float*)d_in[13];
  const float* W_aoa    = (const float*)d_in[14];
  const float* b_aoa    = (const float*)d_in[15];
  const float* pred_v   = (const float*)d_in[16];
  const float* pred_g   = (const float*)d_in[17];
  const float* pred_b   = (const float*)d_in[18];
  float* out = (float*)d_out;

  char* base = (char*)d_ws;
  size_t off = 0;
  auto alloc = [&](size_t bytes) -> char* {
    char* p = base + off;
    off = (off + bytes + 255) & ~(size_t)255;
    return p;
  };
  // persistent
  unsigned short* KV     = (unsigned short*)alloc((size_t)BB * NN * 2048 * 2);
  unsigned short* WcatI  = (unsigned short*)alloc((size_t)4096 * 3072 * 2);
  unsigned short* WaoaI  = (unsigned short*)alloc((size_t)2048 * 2048 * 2);
  unsigned short* Wq_b   = (unsigned short*)alloc((size_t)DD * DD * 2);
  unsigned short* Wkv_b  = (unsigned short*)alloc((size_t)2048 * 1024 * 2);
  float* bcombI          = (float*)alloc(4096 * 4);
  float* baoaI           = (float*)alloc(2048 * 4);
  float* bkv             = (float*)alloc(2048 * 4);
  float* meanf           = (float*)alloc((size_t)BB * DD * 4);
  float* mbuf            = (float*)alloc((size_t)BB * DD * 4);
  unsigned short* embAll = (unsigned short*)alloc((size_t)TT * BB * DD * 2);
  unsigned short* x2     = (unsigned short*)alloc((size_t)2 * BB * 2048 * 2);
  // union: encb (precompute only) | { Eall, predinAll, xaoa, qbuf } (step phase)
  // Wn (final vocab) overlays dead Eall after the loop.
  char* uni = alloc((size_t)BB * NN * DD * 2);   // 51.4 MB
  unsigned short* encb = (unsigned short*)uni;
  size_t ua = 0;
  auto carve = [&](size_t b) -> char* { char* p = uni + ua; ua = (ua + b + 255) & ~(size_t)255; return p; };
  float* Eall              = (float*)carve((size_t)TT * BB * 4096 * 4);   // 41.9 MB
  unsigned short* predinAll= (unsigned short*)carve((size_t)TT * BB * DD * 2);
  unsigned short* xaoa     = (unsigned short*)carve((size_t)BB * 2048 * 2);
  float* qbuf              = (float*)carve((size_t)2 * BB * DD * 4);
  unsigned short* Wn_b     = (unsigned short*)uni;                        // 20.5 MB over Eall
  if (off > ws_size || ua > (size_t)BB * NN * DD * 2) return;

  // ---- precompute ----
  meanconv_kernel<<<512, 256, 0, stream>>>(enc, meanf, encb);
  wcatI_kernel<<<12288, 256, 0, stream>>>(W_ih, W_hh, WcatI);
  conv4_kernel<<<1024, 256, 0, stream>>>(Wq, Wq_b);
  waoaI_kernel<<<4096, 256, 0, stream>>>(W_aoa, WaoaI);
  kvw4_kernel<<<2048, 256, 0, stream>>>(Wk, Wv, Wkv_b);
  bias_kernel<<<16, 256, 0, stream>>>(b_ih, b_hh, b_aoa, bk, bv, bcombI, baoaI, bkv);
  emb4_kernel<<<2560, 256, 0, stream>>>(embed_W, captions, embAll);
  init_kernel<<<512, 256, 0, stream>>>(meanf, mbuf, x2);
  // KV projection: 196 rowtiles x 16 coltiles, BN=128, DEPTH=2
  gemmp<128, 1, 2><<<3136, 256, 0, stream>>>(encb, 1024, Wkv_b, 1024, 16, 2048, 16, bkv,
                                             nullptr, KV, nullptr, nullptr, nullptr, nullptr, nullptr);
  // encb dead -> Eall etc. usable. Eall = embAll @ WcatI[:, :1024]^T  (20 rowtiles x 128)
  gemmp<32, 0, 3><<<2560, 256, 0, stream>>>(embAll, 1024, WcatI, 3072, 16, 4096, 128, nullptr,
                                            Eall, nullptr, nullptr, nullptr, nullptr, nullptr, nullptr);

  // ---- 20 recurrent steps (4 kernels/step) ----
  for (int t = 0; t < TT; ++t) {
    unsigned short* xc = x2 + (size_t)(t & 1) * BB * 2048;
    unsigned short* xn = x2 + (size_t)((t + 1) & 1) * BB * 2048;
    // gates: K-slice 2048 (W cols 1024..3071), + Eall[t] + LSTM epilogue
    gemmp<32, 3, 3><<<128, 256, 0, stream>>>(xc, 2048, WcatI + 1024, 3072, 32, 4096, 128, bcombI,
                                             Eall + (size_t)t * BB * 4096, nullptr, mbuf, nullptr, xaoa, xn, nullptr);
    // q: split-K x2 (nkt=8 each)
    gemmp<32, 5, 3><<<64, 256, 0, stream>>>(xaoa + 1024, 2048, Wq_b, 1024, 8, 1024, 32, nullptr,
                                            qbuf, nullptr, nullptr, nullptr, nullptr, nullptr, nullptr);
    attn_kernel<<<BB * NHH, 256, 0, stream>>>(qbuf, bq, KV, xaoa);
    // aoa + GLU
    gemmp<32, 4, 3><<<64, 256, 0, stream>>>(xaoa, 2048, WaoaI, 2048, 32, 2048, 64, baoaI,
                                            nullptr, predinAll + (size_t)t * BB * DD, nullptr, meanf, nullptr, xn, nullptr);
  }

  // weight-norm matrix (overlays dead Eall), then one batched vocab GEMM
  wn_kernel<<<VV, 256, 0, stream>>>(pred_v, pred_g, Wn_b);
  gemmp<32, 2, 3><<<20 * 313, 256, 0, stream>>>(predinAll, 1024, Wn_b, 1024, 16, VV, 313, pred_b,
                                                out, nullptr, nullptr, nullptr, nullptr, nullptr, lengths);
}